// Round 3
// baseline (5746.328 us; speedup 1.0000x reference)
//
#include <hip/hip_runtime.h>

// ---------------------------------------------------------------------------
// LinearDecoder: MLP encoder -> 64-step LSTM decoder with softmax/sigmoid head
// B=8192, LAT=256, MLP=512, HID=512, INP=128, T=64, gates N=2048, K=640
// Decoder = ONE persistent kernel (256 blocks, 512 thr, 128KB LDS), 8-block
// group barriers (rows are group-private), 8-phase gate GEMM + fused head.
// ---------------------------------------------------------------------------

typedef _Float16 h16;
typedef __attribute__((ext_vector_type(8))) _Float16 f16x8;
typedef __attribute__((ext_vector_type(4))) float f32x4;

#define BB 8192
#define TT 64

__device__ __forceinline__ void gload16(const void* g, void* lds) {
  __builtin_amdgcn_global_load_lds(
      (const __attribute__((address_space(1))) unsigned int*)g,
      (__attribute__((address_space(3))) unsigned int*)lds, 16, 0, 0);
}

__device__ __forceinline__ float sigm(float x) { return 1.f / (1.f + __expf(-x)); }
__device__ __forceinline__ float tanhf_(float x) { return 2.f / (1.f + __expf(-2.f * x)) - 1.f; }

#define MIDBAR_LG()                                        \
  do {                                                     \
    __builtin_amdgcn_s_barrier();                          \
    asm volatile("s_waitcnt lgkmcnt(0)" ::: "memory");     \
    __builtin_amdgcn_sched_barrier(0);                     \
  } while (0)
#define ENDBAR()                                           \
  do {                                                     \
    __builtin_amdgcn_s_barrier();                          \
    asm volatile("" ::: "memory");                         \
  } while (0)

// ---------------------------------------------------------------------------
// Persistent decoder. grid=256, block=512. Group g owns rows g*256..+255;
// member j owns gate-col block j*256..+255 (n') and head rows g*256+j*32..+31.
// bid mapping keeps a group's 8 members on one XCD (bid%8 == g%8).
// ---------------------------------------------------------------------------
__global__ __launch_bounds__(512, 2) void decoder_persist(
    h16* __restrict__ XHa, h16* __restrict__ XHb,
    const h16* __restrict__ Bt, const float* __restrict__ bg,
    const h16* __restrict__ WpT, const float* __restrict__ bp,
    float* __restrict__ Cbuf, float* __restrict__ yout,
    unsigned int* __restrict__ barcnt) {
  __shared__ __align__(16) h16 As[2][16384];
  __shared__ __align__(16) h16 Bs[2][16384];
  const int tid = threadIdx.x;
  const int lane = tid & 63;
  const int wid = tid >> 6;
  const int wr = wid >> 2, wc = wid & 3;
  const int bid = blockIdx.x;
  const int g = ((bid >> 6) << 3) | (bid & 7);
  const int j = (bid >> 3) & 7;
  const int m0 = g * 256;
  const int n0 = j * 256;
  const int arow = lane & 15, khi = lane >> 4;
  const int x7 = arow & 7;
  unsigned int* cnt = barcnt + g * 32;  // 128B-padded per group
  unsigned int bargen = 0;

  auto stage = [&](h16(*dst)[16384], int slot, int h, const h16* src, int base,
                   int kt) {
#pragma unroll
    for (int li = 0; li < 2; ++li) {
      int rowbase = li * 128 + h * 64 + wid * 8;  // wave-uniform
      int row = rowbase + (lane >> 3);
      int gc = (lane & 7) ^ (lane >> 3);
      gload16(src + (size_t)(base + row) * 640 + kt * 64 + gc * 8,
              &dst[slot][rowbase * 64]);
    }
  };

  f32x4 acc[8][4];
  f16x8 af[4], bf[2][4];

  auto readA = [&](int slot, int ms, int ks) {
#pragma unroll
    for (int mr = 0; mr < 4; ++mr) {
      int r = wr * 128 + ms * 64 + mr * 16 + arow;
      af[mr] = *(const f16x8*)&As[slot][r * 64 + ((ks * 4 + khi) ^ x7) * 8];
    }
  };
  auto readB = [&](int slot, int ks) {
#pragma unroll
    for (int jj = 0; jj < 4; ++jj) {
      int rb = wc * 64 + jj * 16 + arow;
      bf[ks][jj] = *(const f16x8*)&Bs[slot][rb * 64 + ((ks * 4 + khi) ^ x7) * 8];
    }
  };
  auto mfma16 = [&](int ms, int ks) {
    __builtin_amdgcn_s_setprio(1);
#pragma unroll
    for (int mr = 0; mr < 4; ++mr)
#pragma unroll
      for (int jj = 0; jj < 4; ++jj)
        acc[ms * 4 + mr][jj] = __builtin_amdgcn_mfma_f32_16x16x32_f16(
            af[mr], bf[ks][jj], acc[ms * 4 + mr][jj], 0, 0, 0);
    __builtin_amdgcn_s_setprio(0);
  };

  // loop-invariant gate biases (verified permutation from round 2)
  const int nb = n0 + wc * 64;
  const float bI = bg[nb + arow];
  const float bF = bg[nb + 16 + arow];
  const float bG = bg[nb + 32 + arow];
  const float bO = bg[nb + 48 + arow];
  const int hj = j * 64 + wc * 16 + arow;

#pragma unroll 1
  for (int t = 0; t < TT; ++t) {
    h16* Ain = (t & 1) ? XHb : XHa;
    h16* Aout = (t & 1) ? XHa : XHb;

    // ---- barrier A (xh_t ready) with B-tile prefetch hidden under spin ----
    __syncthreads();
    if (tid == 0)
      __hip_atomic_fetch_add(cnt, 1u, __ATOMIC_RELEASE, __HIP_MEMORY_SCOPE_AGENT);
    ++bargen;
    stage(Bs, 0, 0, Bt, n0, 0);
    stage(Bs, 0, 1, Bt, n0, 0);
    stage(Bs, 1, 0, Bt, n0, 1);
    stage(Bs, 1, 1, Bt, n0, 1);
    if (tid == 0) {
      unsigned int tgt = bargen * 8u;
      while (__hip_atomic_load(cnt, __ATOMIC_RELAXED, __HIP_MEMORY_SCOPE_AGENT) < tgt)
        __builtin_amdgcn_s_sleep(1);
      __hip_atomic_fetch_add(cnt, 0u, __ATOMIC_ACQUIRE, __HIP_MEMORY_SCOPE_AGENT);
    }
    __syncthreads();

    // A prologue (post-barrier: reads fresh xh)
    stage(As, 0, 0, Ain, m0, 0);
    stage(As, 0, 1, Ain, m0, 0);
    stage(As, 1, 0, Ain, m0, 1);
    asm volatile("s_waitcnt vmcnt(4)" ::: "memory");
    __builtin_amdgcn_s_barrier();

#pragma unroll
    for (int i = 0; i < 8; ++i)
#pragma unroll
      for (int jj = 0; jj < 4; ++jj) acc[i][jj] = (f32x4)0.f;

#pragma unroll 1
    for (int i = 0; i < 5; ++i) {
      const int t2 = 2 * i + 2, t3 = 2 * i + 3;
      // P1
      readB(0, 0);
      readB(0, 1);
      readA(0, 0, 0);
      stage(As, 1, 1, Ain, m0, 2 * i + 1);
      MIDBAR_LG();
      mfma16(0, 0);
      ENDBAR();
      // P2
      readA(0, 0, 1);
      if (t2 < 10) stage(Bs, 0, 0, Bt, n0, t2);
      if (i == 0) asm volatile("s_waitcnt vmcnt(6)" ::: "memory");
      MIDBAR_LG();
      mfma16(0, 1);
      ENDBAR();
      // P3
      readA(0, 1, 0);
      if (t2 < 10) stage(Bs, 0, 1, Bt, n0, t2);
      MIDBAR_LG();
      mfma16(1, 0);
      ENDBAR();
      // P4
      readA(0, 1, 1);
      if (t2 < 10) stage(As, 0, 0, Ain, m0, t2);
      if (i < 4)
        asm volatile("s_waitcnt vmcnt(6)" ::: "memory");
      else
        asm volatile("s_waitcnt vmcnt(0)" ::: "memory");
      MIDBAR_LG();
      mfma16(1, 1);
      ENDBAR();
      // P5
      readB(1, 0);
      readB(1, 1);
      readA(1, 0, 0);
      if (t2 < 10) stage(As, 0, 1, Ain, m0, t2);
      MIDBAR_LG();
      mfma16(0, 0);
      ENDBAR();
      // P6
      readA(1, 0, 1);
      if (t3 < 10) stage(Bs, 1, 0, Bt, n0, t3);
      MIDBAR_LG();
      mfma16(0, 1);
      ENDBAR();
      // P7
      readA(1, 1, 0);
      if (t3 < 10) stage(Bs, 1, 1, Bt, n0, t3);
      MIDBAR_LG();
      mfma16(1, 0);
      ENDBAR();
      // P8
      readA(1, 1, 1);
      if (t3 < 10) stage(As, 1, 0, Ain, m0, t3);
      if (i < 4)
        asm volatile("s_waitcnt vmcnt(6)" ::: "memory");
      else
        asm volatile("s_waitcnt vmcnt(0)" ::: "memory");
      MIDBAR_LG();
      mfma16(1, 1);
      ENDBAR();
    }

    // ---- gate epilogue: LSTM cell update ----
#pragma unroll
    for (int mrep = 0; mrep < 8; ++mrep) {
#pragma unroll
      for (int r = 0; r < 4; ++r) {
        int m = m0 + wr * 128 + mrep * 16 + khi * 4 + r;
        float gi = sigm(acc[mrep][0][r] + bI);
        float gf = sigm(acc[mrep][1][r] + bF);
        float gg = tanhf_(acc[mrep][2][r] + bG);
        float go = sigm(acc[mrep][3][r] + bO);
        size_t ci = (size_t)m * 512 + hj;
        float c2 = gf * Cbuf[ci] + gi * gg;
        Cbuf[ci] = c2;
        Aout[(size_t)m * 640 + 128 + hj] = (h16)(go * tanhf_(c2));
      }
    }

    // ---- barrier B (h_t ready) with Wp-fragment prefetch under spin ----
    __syncthreads();
    if (tid == 0)
      __hip_atomic_fetch_add(cnt, 1u, __ATOMIC_RELEASE, __HIP_MEMORY_SCOPE_AGENT);
    ++bargen;
    f16x8 wfr[16];
#pragma unroll
    for (int kf = 0; kf < 16; ++kf)
      wfr[kf] = *(const f16x8*)&WpT[(size_t)(wid * 16 + arow) * 512 + kf * 32 + khi * 8];
    if (tid == 0) {
      unsigned int tgt = bargen * 8u;
      while (__hip_atomic_load(cnt, __ATOMIC_RELAXED, __HIP_MEMORY_SCOPE_AGENT) < tgt)
        __builtin_amdgcn_s_sleep(1);
      __hip_atomic_fetch_add(cnt, 0u, __ATOMIC_ACQUIRE, __HIP_MEMORY_SCOPE_AGENT);
    }
    __syncthreads();

    // ---- head: rows r0..r0+31, logits = h @ WpT^T + bp, softmax/sigmoid ----
    {
      h16* hst = (h16*)As;    // 32 KB
      float* lgs = (float*)Bs;  // 16 KB
      const int r0 = m0 + j * 32;
      {
        int row = tid >> 4;  // 0..31
        int cg = tid & 15;   // 64B chunk group
        const h16* src = Aout + (size_t)(r0 + row) * 640 + 128 + cg * 32;
#pragma unroll
        for (int q = 0; q < 4; ++q) {
          int c = cg * 4 + q;
          f16x8 v = *(const f16x8*)(src + q * 8);
          *(f16x8*)&hst[row * 512 + (c ^ (row & 7)) * 8] = v;
        }
      }
      __syncthreads();
      f32x4 hacc[2] = {(f32x4)0.f, (f32x4)0.f};
#pragma unroll
      for (int kf = 0; kf < 16; ++kf) {
#pragma unroll
        for (int mf = 0; mf < 2; ++mf) {
          int row = mf * 16 + arow;
          f16x8 afr = *(const f16x8*)&hst[row * 512 + ((kf * 4 + khi) ^ (row & 7)) * 8];
          hacc[mf] = __builtin_amdgcn_mfma_f32_16x16x32_f16(afr, wfr[kf], hacc[mf], 0, 0, 0);
        }
      }
#pragma unroll
      for (int mf = 0; mf < 2; ++mf)
#pragma unroll
        for (int r = 0; r < 4; ++r)
          lgs[(mf * 16 + khi * 4 + r) * 128 + wid * 16 + arow] = hacc[mf][r];
      __syncthreads();
      {
        int row = tid >> 4, cg = tid & 15;
        float v[8];
        float mx = -1e30f;
#pragma unroll
        for (int q = 0; q < 8; ++q) {
          int col = cg * 8 + q;
          v[q] = lgs[row * 128 + col] + bp[col];
          if (col != 127) mx = fmaxf(mx, v[q]);
        }
#pragma unroll
        for (int s = 1; s < 16; s <<= 1) mx = fmaxf(mx, __shfl_xor(mx, s, 16));
        float sm = 0.f;
#pragma unroll
        for (int q = 0; q < 8; ++q) {
          int col = cg * 8 + q;
          if (col != 127) sm += __expf(v[q] - mx);
        }
#pragma unroll
        for (int s = 1; s < 16; s <<= 1) sm += __shfl_xor(sm, s, 16);
        float inv = 1.f / sm;
        h16 xo[8];
        float yo[8];
#pragma unroll
        for (int q = 0; q < 8; ++q) {
          int col = cg * 8 + q;
          float res = (col == 127) ? sigm(v[q]) : __expf(v[q] - mx) * inv;
          xo[q] = (h16)res;
          yo[q] = res;
        }
        *(f16x8*)&Aout[(size_t)(r0 + row) * 640 + cg * 8] = *(f16x8*)xo;
        float* yd = yout + (((size_t)(r0 + row)) * 64 + t) * 128 + cg * 8;
        *(f32x4*)yd = *(f32x4*)&yo[0];
        *(f32x4*)(yd + 4) = *(f32x4*)&yo[4];
      }
    }
  }
}

// ---------------------------------------------------------------------------
// Head GEMM for encoder x0 (verified round-2 structure)
// ---------------------------------------------------------------------------
__global__ __launch_bounds__(256) void head_gemm2(
    const h16* __restrict__ A, int lda, const h16* __restrict__ Bt,
    const float* __restrict__ bias, int nkt, h16* __restrict__ Xout,
    float* __restrict__ ydst, int tstep) {
  __shared__ __align__(16) h16 As[2][64 * 64];
  __shared__ __align__(16) h16 Bs[2][128 * 64];
  const int tid = threadIdx.x;
  const int lane = tid & 63;
  const int w = tid >> 6;
  const int m0 = blockIdx.x * 64;
  const int arow = lane & 15, khi = lane >> 4;
  const int x7 = arow & 7;

  auto stageA = [&](int slot, int kt) {
#pragma unroll
    for (int li = 0; li < 2; ++li) {
      int rowbase = li * 32 + w * 8;
      int row = rowbase + (lane >> 3);
      int gc = (lane & 7) ^ (lane >> 3);
      gload16(A + (size_t)(m0 + row) * lda + kt * 64 + gc * 8,
              &As[slot][rowbase * 64]);
    }
  };
  auto stageB = [&](int slot, int kt) {
#pragma unroll
    for (int li = 0; li < 4; ++li) {
      int rowbase = li * 32 + w * 8;
      int row = rowbase + (lane >> 3);
      int gc = (lane & 7) ^ (lane >> 3);
      gload16(Bt + (size_t)row * 512 + kt * 64 + gc * 8, &Bs[slot][rowbase * 64]);
    }
  };

  f32x4 acc[8];
#pragma unroll
  for (int jj = 0; jj < 8; ++jj) acc[jj] = (f32x4)0.f;

  stageA(0, 0);
  stageB(0, 0);
#pragma unroll 1
  for (int kt = 0; kt < nkt; ++kt) {
    int p = kt & 1;
    if (kt + 1 < nkt) {
      stageA(p ^ 1, kt + 1);
      stageB(p ^ 1, kt + 1);
      asm volatile("s_waitcnt vmcnt(6)" ::: "memory");
    } else {
      asm volatile("s_waitcnt vmcnt(0)" ::: "memory");
    }
    ENDBAR();
#pragma unroll
    for (int kk = 0; kk < 2; ++kk) {
      int kc = kk * 4 + khi;
      int ra = w * 16 + arow;
      f16x8 afr = *(const f16x8*)&As[p][ra * 64 + (kc ^ x7) * 8];
#pragma unroll
      for (int nt = 0; nt < 8; ++nt) {
        int rb = nt * 16 + arow;
        f16x8 bfr = *(const f16x8*)&Bs[p][rb * 64 + (kc ^ x7) * 8];
        acc[nt] = __builtin_amdgcn_mfma_f32_16x16x32_f16(afr, bfr, acc[nt], 0, 0, 0);
      }
    }
    ENDBAR();
  }

#pragma unroll
  for (int r = 0; r < 4; ++r) {
    int m = m0 + w * 16 + khi * 4 + r;
    float v[8];
    float mx = -1e30f;
#pragma unroll
    for (int nt = 0; nt < 8; ++nt) {
      int col = nt * 16 + arow;
      v[nt] = acc[nt][r] + bias[col];
      if (col != 127) mx = fmaxf(mx, v[nt]);
    }
#pragma unroll
    for (int s = 1; s < 16; s <<= 1) mx = fmaxf(mx, __shfl_xor(mx, s, 16));
    float sm = 0.f;
#pragma unroll
    for (int nt = 0; nt < 8; ++nt) {
      int col = nt * 16 + arow;
      if (col != 127) sm += __expf(v[nt] - mx);
    }
#pragma unroll
    for (int s = 1; s < 16; s <<= 1) sm += __shfl_xor(sm, s, 16);
    float inv = 1.f / sm;
#pragma unroll
    for (int nt = 0; nt < 8; ++nt) {
      int col = nt * 16 + arow;
      float res = (col == 127) ? sigm(v[nt]) : __expf(v[nt] - mx) * inv;
      Xout[(size_t)m * 640 + col] = (h16)res;
      if (ydst) ydst[((size_t)m * 64 + tstep) * 128 + col] = res;
    }
  }
}

// ---------------------------------------------------------------------------
// Encoder GEMM (verified round-1 structure, 128x128 tile)
// ---------------------------------------------------------------------------
enum { EP_LRELU = 0, EP_LIN16 = 1, EP_F32 = 2 };

template <int EP>
__global__ __launch_bounds__(256) void gemm128(
    const h16* __restrict__ A, int lda, const h16* __restrict__ Bt,
    const float* __restrict__ bias, int K, h16* __restrict__ out16, int ldo,
    int ocol, float* __restrict__ outf, int ldf) {
  __shared__ __align__(16) h16 As[128 * 64];
  __shared__ __align__(16) h16 Bs[128 * 64];
  const int tid = threadIdx.x;
  const int lane = tid & 63;
  const int w = tid >> 6;
  const int m0 = blockIdx.x * 128;
  const int n0 = blockIdx.y * 128;

  f32x4 acc[4][4];
#pragma unroll
  for (int i = 0; i < 4; ++i)
#pragma unroll
    for (int jj = 0; jj < 4; ++jj) acc[i][jj] = (f32x4)0.f;

  const int rh = (w >> 1) * 64;
  const int arow = lane & 15;
  const int khi = lane >> 4;

  const int nkt = K >> 6;
  for (int kt = 0; kt < nkt; ++kt) {
#pragma unroll
    for (int li = 0; li < 4; ++li) {
      int L = w * 4 + li;
      int r = L * 8 + (lane >> 3);
      int c = lane & 7;
      int gc = c ^ (r & 7);
      gload16(A + (size_t)(m0 + r) * lda + kt * 64 + gc * 8, &As[L * 512]);
      gload16(Bt + (size_t)(n0 + r) * K + kt * 64 + gc * 8, &Bs[L * 512]);
    }
    __syncthreads();
#pragma unroll
    for (int kk = 0; kk < 2; ++kk) {
      const int kc = kk * 4 + khi;
      f16x8 af[4], bf[4];
#pragma unroll
      for (int mt = 0; mt < 4; ++mt) {
        int r = rh + mt * 16 + arow;
        af[mt] = *(const f16x8*)&As[r * 64 + (kc ^ (r & 7)) * 8];
      }
#pragma unroll
      for (int jj = 0; jj < 4; ++jj) {
        int nt = (w & 1) * 4 + jj;
        int r = nt * 16 + arow;
        bf[jj] = *(const f16x8*)&Bs[r * 64 + (kc ^ (r & 7)) * 8];
      }
#pragma unroll
      for (int mt = 0; mt < 4; ++mt)
#pragma unroll
        for (int jj = 0; jj < 4; ++jj)
          acc[mt][jj] =
              __builtin_amdgcn_mfma_f32_16x16x32_f16(af[mt], bf[jj], acc[mt][jj], 0, 0, 0);
    }
    __syncthreads();
  }

#pragma unroll
  for (int mt = 0; mt < 4; ++mt) {
#pragma unroll
    for (int jj = 0; jj < 4; ++jj) {
      int nt = (w & 1) * 4 + jj;
      int n = n0 + nt * 16 + arow;
      float bv = bias[n];
#pragma unroll
      for (int r = 0; r < 4; ++r) {
        int m = m0 + rh + mt * 16 + khi * 4 + r;
        float v = acc[mt][jj][r] + bv;
        if constexpr (EP == EP_LRELU) {
          v = v >= 0.f ? v : 0.2f * v;
          out16[(size_t)m * ldo + n] = (h16)v;
        } else if constexpr (EP == EP_LIN16) {
          out16[(size_t)m * ldo + ocol + n] = (h16)v;
        } else {
          outf[(size_t)m * ldf + n] = v;
        }
      }
    }
  }
}

// ---------------- prep kernels ----------------
__global__ void cvt16(const float* __restrict__ in, h16* __restrict__ out, int n) {
  int i = blockIdx.x * 256 + threadIdx.x;
  if (i < n) out[i] = (h16)in[i];
}

__global__ void transposeW(const float* __restrict__ W, h16* __restrict__ WT, int K,
                           int N) {
  int i = blockIdx.x * 256 + threadIdx.x;
  if (i >= K * N) return;
  int k = i / N, n = i % N;
  WT[(size_t)n * K + k] = (h16)W[i];
}

// WgT[n'][640]: n' = by*256 + wc*64 + q*16 + jj -> orig = q*512 + by*64 + wc*16 + jj
__global__ void prep_gate(const float* __restrict__ Wih, const float* __restrict__ Whh,
                          const float* __restrict__ bih, const float* __restrict__ bhh,
                          h16* __restrict__ WgT, float* __restrict__ bg) {
  int i = blockIdx.x * 256 + threadIdx.x;
  if (i >= 2048 * 640) return;
  int np = i / 640, k = i % 640;
  int by = np >> 8, wcc = (np >> 6) & 3, q = (np >> 4) & 3, jj = np & 15;
  int orig = q * 512 + by * 64 + wcc * 16 + jj;
  float wv = (k < 128) ? Wih[(size_t)k * 2048 + orig]
                       : Whh[(size_t)(k - 128) * 2048 + orig];
  WgT[i] = (h16)wv;
  if (k == 0) bg[np] = bih[orig] + bhh[orig];
}

// ---------------- launch ----------------
extern "C" void kernel_launch(void* const* d_in, const int* in_sizes, int n_in,
                              void* d_out, int out_size, void* d_ws, size_t ws_size,
                              hipStream_t stream) {
  const float* x = (const float*)d_in[0];
  const float* W1 = (const float*)d_in[1];
  const float* b1 = (const float*)d_in[2];
  const float* W2 = (const float*)d_in[3];
  const float* b2 = (const float*)d_in[4];
  const float* W3 = (const float*)d_in[5];
  const float* b3 = (const float*)d_in[6];
  const float* Wh1 = (const float*)d_in[7];
  const float* bh1 = (const float*)d_in[8];
  const float* Wh2 = (const float*)d_in[9];
  const float* bh2 = (const float*)d_in[10];
  const float* Wc1 = (const float*)d_in[11];
  const float* bc1 = (const float*)d_in[12];
  const float* Wc2 = (const float*)d_in[13];
  const float* bc2 = (const float*)d_in[14];
  const float* Wx1 = (const float*)d_in[15];
  const float* bx1 = (const float*)d_in[16];
  const float* Wx2 = (const float*)d_in[17];
  const float* bx2 = (const float*)d_in[18];
  const float* Wih = (const float*)d_in[19];
  const float* bih = (const float*)d_in[20];
  const float* Whh = (const float*)d_in[21];
  const float* bhh = (const float*)d_in[22];
  const float* Wp = (const float*)d_in[23];
  const float* bp = (const float*)d_in[24];

  char* ws = (char*)d_ws;
  size_t off = 0;
  auto take = [&](size_t bytes) -> void* {
    void* p = ws + off;
    off += (bytes + 255) & ~(size_t)255;
    return p;
  };
  h16* X16 = (h16*)take((size_t)BB * 256 * 2);
  h16* Za = (h16*)take((size_t)BB * 512 * 2);
  h16* Zb = (h16*)take((size_t)BB * 512 * 2);
  h16* XHa = (h16*)take((size_t)BB * 640 * 2);
  h16* XHb = (h16*)take((size_t)BB * 640 * 2);
  float* C = (float*)take((size_t)BB * 512 * 4);
  h16* W1T = (h16*)take(256 * 512 * 2);
  h16* W2T = (h16*)take(512 * 512 * 2);
  h16* W3T = (h16*)take(512 * 512 * 2);
  h16* Wh1T = (h16*)take(512 * 512 * 2);
  h16* Wh2T = (h16*)take(512 * 512 * 2);
  h16* Wc1T = (h16*)take(512 * 512 * 2);
  h16* Wc2T = (h16*)take(512 * 512 * 2);
  h16* Wx1T = (h16*)take(512 * 512 * 2);
  h16* Wx2T = (h16*)take(128 * 512 * 2);
  h16* WpT = (h16*)take(128 * 512 * 2);
  h16* WgT = (h16*)take((size_t)2048 * 640 * 2);
  float* bg = (float*)take(2048 * 4);
  unsigned int* barcnt = (unsigned int*)take(32 * 32 * 4);

  hipMemsetAsync(barcnt, 0, 32 * 32 * 4, stream);

  dim3 blk(256);
  cvt16<<<(BB * 256 + 255) / 256, blk, 0, stream>>>(x, X16, BB * 256);
  transposeW<<<(256 * 512 + 255) / 256, blk, 0, stream>>>(W1, W1T, 256, 512);
  transposeW<<<(512 * 512 + 255) / 256, blk, 0, stream>>>(W2, W2T, 512, 512);
  transposeW<<<(512 * 512 + 255) / 256, blk, 0, stream>>>(W3, W3T, 512, 512);
  transposeW<<<(512 * 512 + 255) / 256, blk, 0, stream>>>(Wh1, Wh1T, 512, 512);
  transposeW<<<(512 * 512 + 255) / 256, blk, 0, stream>>>(Wh2, Wh2T, 512, 512);
  transposeW<<<(512 * 512 + 255) / 256, blk, 0, stream>>>(Wc1, Wc1T, 512, 512);
  transposeW<<<(512 * 512 + 255) / 256, blk, 0, stream>>>(Wc2, Wc2T, 512, 512);
  transposeW<<<(512 * 512 + 255) / 256, blk, 0, stream>>>(Wx1, Wx1T, 512, 512);
  transposeW<<<(512 * 128 + 255) / 256, blk, 0, stream>>>(Wx2, Wx2T, 512, 128);
  transposeW<<<(512 * 128 + 255) / 256, blk, 0, stream>>>(Wp, WpT, 512, 128);
  prep_gate<<<(2048 * 640 + 255) / 256, blk, 0, stream>>>(Wih, Whh, bih, bhh, WgT, bg);

  // MLP encoder
  gemm128<EP_LRELU><<<dim3(64, 4), blk, 0, stream>>>(X16, 256, W1T, b1, 256, Za, 512, 0, nullptr, 0);
  gemm128<EP_LRELU><<<dim3(64, 4), blk, 0, stream>>>(Za, 512, W2T, b2, 512, Zb, 512, 0, nullptr, 0);
  gemm128<EP_LRELU><<<dim3(64, 4), blk, 0, stream>>>(Zb, 512, W3T, b3, 512, Za, 512, 0, nullptr, 0);
  gemm128<EP_LRELU><<<dim3(64, 4), blk, 0, stream>>>(Za, 512, Wh1T, bh1, 512, Zb, 512, 0, nullptr, 0);
  gemm128<EP_LIN16><<<dim3(64, 4), blk, 0, stream>>>(Zb, 512, Wh2T, bh2, 512, XHa, 640, 128, nullptr, 0);
  gemm128<EP_LRELU><<<dim3(64, 4), blk, 0, stream>>>(Za, 512, Wc1T, bc1, 512, Zb, 512, 0, nullptr, 0);
  gemm128<EP_F32><<<dim3(64, 4), blk, 0, stream>>>(Zb, 512, Wc2T, bc2, 512, nullptr, 0, 0, C, 512);
  gemm128<EP_LRELU><<<dim3(64, 4), blk, 0, stream>>>(Za, 512, Wx1T, bx1, 512, Zb, 512, 0, nullptr, 0);
  head_gemm2<<<128, blk, 0, stream>>>(Zb, 512, Wx2T, bx2, 8, XHa, nullptr, 0);

  // Persistent LSTM decoder (256 blocks = 1/CU, group barriers)
  decoder_persist<<<dim3(256), dim3(512), 0, stream>>>(
      XHa, XHb, WgT, bg, WpT, bp, C, (float*)d_out, barcnt);
}

// Round 5
// 4942.044 us; speedup vs baseline: 1.1627x; 1.1627x over previous
//
#include <hip/hip_runtime.h>

// ---------------------------------------------------------------------------
// LinearDecoder: MLP encoder -> 64-step LSTM decoder with softmax/sigmoid head
// B=8192, LAT=256, MLP=512, HID=512, INP=128, T=64, gates N=2048, K=640
// Round-2 structure (per-step launches, lockstep phases) + head fused into the
// gate kernel via last-arriver device-scope atomic (no spin, no co-residency).
// ---------------------------------------------------------------------------

typedef _Float16 h16;
typedef __attribute__((ext_vector_type(8))) _Float16 f16x8;
typedef __attribute__((ext_vector_type(4))) float f32x4;

#define BB 8192
#define TT 64

__device__ __forceinline__ void gload16(const void* g, void* lds) {
  __builtin_amdgcn_global_load_lds(
      (const __attribute__((address_space(1))) unsigned int*)g,
      (__attribute__((address_space(3))) unsigned int*)lds, 16, 0, 0);
}

__device__ __forceinline__ float sigm(float x) { return 1.f / (1.f + __expf(-x)); }
__device__ __forceinline__ float tanhf_(float x) { return 2.f / (1.f + __expf(-2.f * x)) - 1.f; }

#define MIDBAR_LG()                                        \
  do {                                                     \
    __builtin_amdgcn_s_barrier();                          \
    asm volatile("s_waitcnt lgkmcnt(0)" ::: "memory");     \
    __builtin_amdgcn_sched_barrier(0);                     \
  } while (0)
#define ENDBAR()                                           \
  do {                                                     \
    __builtin_amdgcn_s_barrier();                          \
    asm volatile("" ::: "memory");                         \
  } while (0)

// ---------------------------------------------------------------------------
// 8-phase 256x256 gate GEMM + fused LSTM cell update + last-arriver head.
// A = XH [8192][640] fp16; Bt = WgT [2048][640] (permuted); K=640 (10 K-tiles).
// Gate col permutation: n' = by*256 + wc*64 + q*16 + jj
//                       orig = q*512 + (by*64 + wc*16 + jj)
// ---------------------------------------------------------------------------
__global__ __launch_bounds__(512, 2) void gate8(
    const h16* __restrict__ A, const h16* __restrict__ Bt,
    const float* __restrict__ bg, float* __restrict__ Cbuf,
    h16* __restrict__ Hout, const h16* __restrict__ WpT,
    const float* __restrict__ bp, float* __restrict__ yout, int tstep,
    unsigned int* __restrict__ hc) {
  __shared__ __align__(16) h16 As[2][16384];
  __shared__ __align__(16) h16 Bs[2][16384];
  const int tid = threadIdx.x;
  const int lane = tid & 63;
  const int wid = tid >> 6;
  const int wr = wid >> 2, wc = wid & 3;
  const int m0 = blockIdx.x * 256;
  const int n0 = blockIdx.y * 256;
  const int arow = lane & 15, khi = lane >> 4;
  const int x7 = arow & 7;

  auto stage = [&](h16(*dst)[16384], int slot, int h, const h16* src, int base,
                   int kt) {
#pragma unroll
    for (int li = 0; li < 2; ++li) {
      int rowbase = li * 128 + h * 64 + wid * 8;  // wave-uniform
      int row = rowbase + (lane >> 3);
      int gc = (lane & 7) ^ (lane >> 3);
      gload16(src + (size_t)(base + row) * 640 + kt * 64 + gc * 8,
              &dst[slot][rowbase * 64]);
    }
  };

  f32x4 acc[8][4];
#pragma unroll
  for (int i = 0; i < 8; ++i)
#pragma unroll
    for (int jj = 0; jj < 4; ++jj) acc[i][jj] = (f32x4)0.f;
  f16x8 af[4], bf[2][4];

  auto readA = [&](int slot, int ms, int ks) {
#pragma unroll
    for (int mr = 0; mr < 4; ++mr) {
      int r = wr * 128 + ms * 64 + mr * 16 + arow;
      af[mr] = *(const f16x8*)&As[slot][r * 64 + ((ks * 4 + khi) ^ x7) * 8];
    }
  };
  auto readB = [&](int slot, int ks) {
#pragma unroll
    for (int jj = 0; jj < 4; ++jj) {
      int rb = wc * 64 + jj * 16 + arow;
      bf[ks][jj] = *(const f16x8*)&Bs[slot][rb * 64 + ((ks * 4 + khi) ^ x7) * 8];
    }
  };
  auto mfma16 = [&](int ms, int ks) {
    __builtin_amdgcn_s_setprio(1);
#pragma unroll
    for (int mr = 0; mr < 4; ++mr)
#pragma unroll
      for (int jj = 0; jj < 4; ++jj)
        acc[ms * 4 + mr][jj] = __builtin_amdgcn_mfma_f32_16x16x32_f16(
            af[mr], bf[ks][jj], acc[ms * 4 + mr][jj], 0, 0, 0);
    __builtin_amdgcn_s_setprio(0);
  };

  // prologue: kt0 fully, kt1 all but A-h1
  stage(Bs, 0, 0, Bt, n0, 0);
  stage(Bs, 0, 1, Bt, n0, 0);
  stage(As, 0, 0, A, m0, 0);
  stage(As, 0, 1, A, m0, 0);
  stage(Bs, 1, 0, Bt, n0, 1);
  stage(Bs, 1, 1, Bt, n0, 1);
  stage(As, 1, 0, A, m0, 1);
  asm volatile("s_waitcnt vmcnt(6)" ::: "memory");
  ENDBAR();

#pragma unroll 1
  for (int i = 0; i < 5; ++i) {
    const int t2 = 2 * i + 2, t3 = 2 * i + 3;
    // P1
    readB(0, 0);
    readB(0, 1);
    readA(0, 0, 0);
    stage(As, 1, 1, A, m0, 2 * i + 1);
    MIDBAR_LG();
    mfma16(0, 0);
    ENDBAR();
    // P2
    readA(0, 0, 1);
    if (t2 < 10) stage(Bs, 0, 0, Bt, n0, t2);
    MIDBAR_LG();
    mfma16(0, 1);
    ENDBAR();
    // P3
    readA(0, 1, 0);
    if (t2 < 10) stage(Bs, 0, 1, Bt, n0, t2);
    MIDBAR_LG();
    mfma16(1, 0);
    ENDBAR();
    // P4
    readA(0, 1, 1);
    if (t2 < 10) stage(As, 0, 0, A, m0, t2);
    if (i < 4)
      asm volatile("s_waitcnt vmcnt(6)" ::: "memory");
    else
      asm volatile("s_waitcnt vmcnt(0)" ::: "memory");
    MIDBAR_LG();
    mfma16(1, 1);
    ENDBAR();
    // P5
    readB(1, 0);
    readB(1, 1);
    readA(1, 0, 0);
    if (t2 < 10) stage(As, 0, 1, A, m0, t2);
    MIDBAR_LG();
    mfma16(0, 0);
    ENDBAR();
    // P6
    readA(1, 0, 1);
    if (t3 < 10) stage(Bs, 1, 0, Bt, n0, t3);
    MIDBAR_LG();
    mfma16(0, 1);
    ENDBAR();
    // P7
    readA(1, 1, 0);
    if (t3 < 10) stage(Bs, 1, 1, Bt, n0, t3);
    MIDBAR_LG();
    mfma16(1, 0);
    ENDBAR();
    // P8
    readA(1, 1, 1);
    if (t3 < 10) stage(As, 1, 0, A, m0, t3);
    if (i < 4)
      asm volatile("s_waitcnt vmcnt(6)" ::: "memory");
    else
      asm volatile("s_waitcnt vmcnt(0)" ::: "memory");
    MIDBAR_LG();
    mfma16(1, 1);
    ENDBAR();
  }

  // ---- gate epilogue: LSTM cell update ----
  const int nb = n0 + wc * 64;
  const float bI = bg[nb + arow];
  const float bF = bg[nb + 16 + arow];
  const float bG = bg[nb + 32 + arow];
  const float bO = bg[nb + 48 + arow];
  const int hj = blockIdx.y * 64 + wc * 16 + arow;
#pragma unroll
  for (int mrep = 0; mrep < 8; ++mrep) {
#pragma unroll
    for (int r = 0; r < 4; ++r) {
      int m = m0 + wr * 128 + mrep * 16 + khi * 4 + r;
      float gi = sigm(acc[mrep][0][r] + bI);
      float gf = sigm(acc[mrep][1][r] + bF);
      float gg = tanhf_(acc[mrep][2][r] + bG);
      float go = sigm(acc[mrep][3][r] + bO);
      size_t ci = (size_t)m * 512 + hj;
      float c2 = gf * Cbuf[ci] + gi * gg;
      Cbuf[ci] = c2;
      Hout[(size_t)m * 640 + 128 + hj] = (h16)(go * tanhf_(c2));
    }
  }

  // ---- last-arriver head: the 8th block per m-tile computes the head ----
  __shared__ unsigned int lastflag;
  __syncthreads();  // all waves' h stores issued (hb edge to tid0's release)
  if (tid == 0) {
    unsigned int old = __hip_atomic_fetch_add(&hc[blockIdx.x], 1u,
                                              __ATOMIC_ACQ_REL,
                                              __HIP_MEMORY_SCOPE_AGENT);
    lastflag = (old == 7u);
  }
  __syncthreads();
  if (!lastflag) return;
  __scoped_atomic_thread_fence(__ATOMIC_ACQUIRE, __MEMORY_SCOPE_DEVICE);

  // head: logits[256][128] = h[256][512] @ WpT^T + bp; softmax/sigmoid.
  // LDS reuse: Hlds = As (64KB = [128][256]), Wlds = Bs (64KB = [128][256]).
  h16* Hlds = (h16*)As;
  h16* Wlds = (h16*)Bs;
  f32x4 ha[2][8];
#pragma unroll 1
  for (int kh = 0; kh < 2; ++kh) {
    // stage Wp K-half: 128 rows x 256 cols
#pragma unroll
    for (int li = 0; li < 8; ++li) {
      int L = wid * 8 + li;
      int row = 2 * L + (lane >> 5);
      int gcc = (lane & 31) ^ (row & 7);
      gload16(WpT + (size_t)row * 512 + kh * 256 + gcc * 8, &Wlds[(2 * L) * 256]);
    }
#pragma unroll 1
    for (int rh2 = 0; rh2 < 2; ++rh2) {
      // stage h rows [m0+rh2*128, +128), K-half kh
#pragma unroll
      for (int li = 0; li < 8; ++li) {
        int L = wid * 8 + li;
        int row = 2 * L + (lane >> 5);
        int gcc = (lane & 31) ^ (row & 7);
        gload16(Hout + (size_t)(m0 + rh2 * 128 + row) * 640 + 128 + kh * 256 + gcc * 8,
                &Hlds[(2 * L) * 256]);
      }
      asm volatile("s_waitcnt vmcnt(0)" ::: "memory");
      __builtin_amdgcn_s_barrier();
      if (kh == 0) {
#pragma unroll
        for (int nt = 0; nt < 8; ++nt) ha[rh2][nt] = (f32x4)0.f;
      }
      int ra = wid * 16 + arow;
#pragma unroll
      for (int ks = 0; ks < 8; ++ks) {
        f16x8 afr = *(const f16x8*)&Hlds[ra * 256 + ((ks * 4 + khi) ^ x7) * 8];
#pragma unroll
        for (int nt = 0; nt < 8; ++nt) {
          int rb = nt * 16 + arow;
          f16x8 bfr = *(const f16x8*)&Wlds[rb * 256 + ((ks * 4 + khi) ^ x7) * 8];
          ha[rh2][nt] =
              __builtin_amdgcn_mfma_f32_16x16x32_f16(afr, bfr, ha[rh2][nt], 0, 0, 0);
        }
      }
      __builtin_amdgcn_s_barrier();  // protect Hlds/Wlds before next stage
    }
  }

  // softmax / sigmoid epilogue + writes
#pragma unroll
  for (int rh2 = 0; rh2 < 2; ++rh2) {
#pragma unroll
    for (int r = 0; r < 4; ++r) {
      int m = m0 + rh2 * 128 + wid * 16 + khi * 4 + r;
      float v[8];
      float mx = -1e30f;
#pragma unroll
      for (int nt = 0; nt < 8; ++nt) {
        int col = nt * 16 + arow;
        v[nt] = ha[rh2][nt][r] + bp[col];
        if (col != 127) mx = fmaxf(mx, v[nt]);
      }
#pragma unroll
      for (int s = 1; s < 16; s <<= 1) mx = fmaxf(mx, __shfl_xor(mx, s, 16));
      float sm = 0.f;
#pragma unroll
      for (int nt = 0; nt < 8; ++nt) {
        int col = nt * 16 + arow;
        if (col != 127) sm += __expf(v[nt] - mx);
      }
#pragma unroll
      for (int s = 1; s < 16; s <<= 1) sm += __shfl_xor(sm, s, 16);
      float inv = 1.f / sm;
#pragma unroll
      for (int nt = 0; nt < 8; ++nt) {
        int col = nt * 16 + arow;
        float res = (col == 127) ? sigm(v[nt]) : __expf(v[nt] - mx) * inv;
        Hout[(size_t)m * 640 + col] = (h16)res;
        yout[((size_t)m * 64 + tstep) * 128 + col] = res;
      }
    }
  }
}

// ---------------------------------------------------------------------------
// Head GEMM for encoder x0 (verified round-2 structure)
// ---------------------------------------------------------------------------
__global__ __launch_bounds__(256) void head_gemm2(
    const h16* __restrict__ A, int lda, const h16* __restrict__ Bt,
    const float* __restrict__ bias, int nkt, h16* __restrict__ Xout,
    float* __restrict__ ydst, int tstep) {
  __shared__ __align__(16) h16 As[2][64 * 64];
  __shared__ __align__(16) h16 Bs[2][128 * 64];
  const int tid = threadIdx.x;
  const int lane = tid & 63;
  const int w = tid >> 6;
  const int m0 = blockIdx.x * 64;
  const int arow = lane & 15, khi = lane >> 4;
  const int x7 = arow & 7;

  auto stageA = [&](int slot, int kt) {
#pragma unroll
    for (int li = 0; li < 2; ++li) {
      int rowbase = li * 32 + w * 8;
      int row = rowbase + (lane >> 3);
      int gc = (lane & 7) ^ (lane >> 3);
      gload16(A + (size_t)(m0 + row) * lda + kt * 64 + gc * 8,
              &As[slot][rowbase * 64]);
    }
  };
  auto stageB = [&](int slot, int kt) {
#pragma unroll
    for (int li = 0; li < 4; ++li) {
      int rowbase = li * 32 + w * 8;
      int row = rowbase + (lane >> 3);
      int gc = (lane & 7) ^ (lane >> 3);
      gload16(Bt + (size_t)row * 512 + kt * 64 + gc * 8, &Bs[slot][rowbase * 64]);
    }
  };

  f32x4 acc[8];
#pragma unroll
  for (int jj = 0; jj < 8; ++jj) acc[jj] = (f32x4)0.f;

  stageA(0, 0);
  stageB(0, 0);
#pragma unroll 1
  for (int kt = 0; kt < nkt; ++kt) {
    int p = kt & 1;
    if (kt + 1 < nkt) {
      stageA(p ^ 1, kt + 1);
      stageB(p ^ 1, kt + 1);
      asm volatile("s_waitcnt vmcnt(6)" ::: "memory");
    } else {
      asm volatile("s_waitcnt vmcnt(0)" ::: "memory");
    }
    ENDBAR();
#pragma unroll
    for (int kk = 0; kk < 2; ++kk) {
      int kc = kk * 4 + khi;
      int ra = w * 16 + arow;
      f16x8 afr = *(const f16x8*)&As[p][ra * 64 + (kc ^ x7) * 8];
#pragma unroll
      for (int nt = 0; nt < 8; ++nt) {
        int rb = nt * 16 + arow;
        f16x8 bfr = *(const f16x8*)&Bs[p][rb * 64 + (kc ^ x7) * 8];
        acc[nt] = __builtin_amdgcn_mfma_f32_16x16x32_f16(afr, bfr, acc[nt], 0, 0, 0);
      }
    }
    ENDBAR();
  }

#pragma unroll
  for (int r = 0; r < 4; ++r) {
    int m = m0 + w * 16 + khi * 4 + r;
    float v[8];
    float mx = -1e30f;
#pragma unroll
    for (int nt = 0; nt < 8; ++nt) {
      int col = nt * 16 + arow;
      v[nt] = acc[nt][r] + bias[col];
      if (col != 127) mx = fmaxf(mx, v[nt]);
    }
#pragma unroll
    for (int s = 1; s < 16; s <<= 1) mx = fmaxf(mx, __shfl_xor(mx, s, 16));
    float sm = 0.f;
#pragma unroll
    for (int nt = 0; nt < 8; ++nt) {
      int col = nt * 16 + arow;
      if (col != 127) sm += __expf(v[nt] - mx);
    }
#pragma unroll
    for (int s = 1; s < 16; s <<= 1) sm += __shfl_xor(sm, s, 16);
    float inv = 1.f / sm;
#pragma unroll
    for (int nt = 0; nt < 8; ++nt) {
      int col = nt * 16 + arow;
      float res = (col == 127) ? sigm(v[nt]) : __expf(v[nt] - mx) * inv;
      Xout[(size_t)m * 640 + col] = (h16)res;
      if (ydst) ydst[((size_t)m * 64 + tstep) * 128 + col] = res;
    }
  }
}

// ---------------------------------------------------------------------------
// Encoder GEMM (verified round-1 structure, 128x128 tile)
// ---------------------------------------------------------------------------
enum { EP_LRELU = 0, EP_LIN16 = 1, EP_F32 = 2 };

template <int EP>
__global__ __launch_bounds__(256) void gemm128(
    const h16* __restrict__ A, int lda, const h16* __restrict__ Bt,
    const float* __restrict__ bias, int K, h16* __restrict__ out16, int ldo,
    int ocol, float* __restrict__ outf, int ldf) {
  __shared__ __align__(16) h16 As[128 * 64];
  __shared__ __align__(16) h16 Bs[128 * 64];
  const int tid = threadIdx.x;
  const int lane = tid & 63;
  const int w = tid >> 6;
  const int m0 = blockIdx.x * 128;
  const int n0 = blockIdx.y * 128;

  f32x4 acc[4][4];
#pragma unroll
  for (int i = 0; i < 4; ++i)
#pragma unroll
    for (int jj = 0; jj < 4; ++jj) acc[i][jj] = (f32x4)0.f;

  const int rh = (w >> 1) * 64;
  const int arow = lane & 15;
  const int khi = lane >> 4;

  const int nkt = K >> 6;
  for (int kt = 0; kt < nkt; ++kt) {
#pragma unroll
    for (int li = 0; li < 4; ++li) {
      int L = w * 4 + li;
      int r = L * 8 + (lane >> 3);
      int c = lane & 7;
      int gc = c ^ (r & 7);
      gload16(A + (size_t)(m0 + r) * lda + kt * 64 + gc * 8, &As[L * 512]);
      gload16(Bt + (size_t)(n0 + r) * K + kt * 64 + gc * 8, &Bs[L * 512]);
    }
    __syncthreads();
#pragma unroll
    for (int kk = 0; kk < 2; ++kk) {
      const int kc = kk * 4 + khi;
      f16x8 af[4], bf[4];
#pragma unroll
      for (int mt = 0; mt < 4; ++mt) {
        int r = rh + mt * 16 + arow;
        af[mt] = *(const f16x8*)&As[r * 64 + (kc ^ (r & 7)) * 8];
      }
#pragma unroll
      for (int jj = 0; jj < 4; ++jj) {
        int nt = (w & 1) * 4 + jj;
        int r = nt * 16 + arow;
        bf[jj] = *(const f16x8*)&Bs[r * 64 + (kc ^ (r & 7)) * 8];
      }
#pragma unroll
      for (int mt = 0; mt < 4; ++mt)
#pragma unroll
        for (int jj = 0; jj < 4; ++jj)
          acc[mt][jj] =
              __builtin_amdgcn_mfma_f32_16x16x32_f16(af[mt], bf[jj], acc[mt][jj], 0, 0, 0);
    }
    __syncthreads();
  }

#pragma unroll
  for (int mt = 0; mt < 4; ++mt) {
#pragma unroll
    for (int jj = 0; jj < 4; ++jj) {
      int nt = (w & 1) * 4 + jj;
      int n = n0 + nt * 16 + arow;
      float bv = bias[n];
#pragma unroll
      for (int r = 0; r < 4; ++r) {
        int m = m0 + rh + mt * 16 + khi * 4 + r;
        float v = acc[mt][jj][r] + bv;
        if constexpr (EP == EP_LRELU) {
          v = v >= 0.f ? v : 0.2f * v;
          out16[(size_t)m * ldo + n] = (h16)v;
        } else if constexpr (EP == EP_LIN16) {
          out16[(size_t)m * ldo + ocol + n] = (h16)v;
        } else {
          outf[(size_t)m * ldf + n] = v;
        }
      }
    }
  }
}

// ---------------- prep kernels ----------------
__global__ void cvt16(const float* __restrict__ in, h16* __restrict__ out, int n) {
  int i = blockIdx.x * 256 + threadIdx.x;
  if (i < n) out[i] = (h16)in[i];
}

__global__ void transposeW(const float* __restrict__ W, h16* __restrict__ WT, int K,
                           int N) {
  int i = blockIdx.x * 256 + threadIdx.x;
  if (i >= K * N) return;
  int k = i / N, n = i % N;
  WT[(size_t)n * K + k] = (h16)W[i];
}

// WgT[n'][640]: n' = by*256 + wc*64 + q*16 + jj -> orig = q*512 + by*64 + wc*16 + jj
__global__ void prep_gate(const float* __restrict__ Wih, const float* __restrict__ Whh,
                          const float* __restrict__ bih, const float* __restrict__ bhh,
                          h16* __restrict__ WgT, float* __restrict__ bg) {
  int i = blockIdx.x * 256 + threadIdx.x;
  if (i >= 2048 * 640) return;
  int np = i / 640, k = i % 640;
  int by = np >> 8, wcc = (np >> 6) & 3, q = (np >> 4) & 3, jj = np & 15;
  int orig = q * 512 + by * 64 + wcc * 16 + jj;
  float wv = (k < 128) ? Wih[(size_t)k * 2048 + orig]
                       : Whh[(size_t)(k - 128) * 2048 + orig];
  WgT[i] = (h16)wv;
  if (k == 0) bg[np] = bih[orig] + bhh[orig];
}

// ---------------- launch ----------------
extern "C" void kernel_launch(void* const* d_in, const int* in_sizes, int n_in,
                              void* d_out, int out_size, void* d_ws, size_t ws_size,
                              hipStream_t stream) {
  const float* x = (const float*)d_in[0];
  const float* W1 = (const float*)d_in[1];
  const float* b1 = (const float*)d_in[2];
  const float* W2 = (const float*)d_in[3];
  const float* b2 = (const float*)d_in[4];
  const float* W3 = (const float*)d_in[5];
  const float* b3 = (const float*)d_in[6];
  const float* Wh1 = (const float*)d_in[7];
  const float* bh1 = (const float*)d_in[8];
  const float* Wh2 = (const float*)d_in[9];
  const float* bh2 = (const float*)d_in[10];
  const float* Wc1 = (const float*)d_in[11];
  const float* bc1 = (const float*)d_in[12];
  const float* Wc2 = (const float*)d_in[13];
  const float* bc2 = (const float*)d_in[14];
  const float* Wx1 = (const float*)d_in[15];
  const float* bx1 = (const float*)d_in[16];
  const float* Wx2 = (const float*)d_in[17];
  const float* bx2 = (const float*)d_in[18];
  const float* Wih = (const float*)d_in[19];
  const float* bih = (const float*)d_in[20];
  const float* Whh = (const float*)d_in[21];
  const float* bhh = (const float*)d_in[22];
  const float* Wp = (const float*)d_in[23];
  const float* bp = (const float*)d_in[24];

  char* ws = (char*)d_ws;
  size_t off = 0;
  auto take = [&](size_t bytes) -> void* {
    void* p = ws + off;
    off += (bytes + 255) & ~(size_t)255;
    return p;
  };
  h16* X16 = (h16*)take((size_t)BB * 256 * 2);
  h16* Za = (h16*)take((size_t)BB * 512 * 2);
  h16* Zb = (h16*)take((size_t)BB * 512 * 2);
  h16* XHa = (h16*)take((size_t)BB * 640 * 2);
  h16* XHb = (h16*)take((size_t)BB * 640 * 2);
  float* C = (float*)take((size_t)BB * 512 * 4);
  h16* W1T = (h16*)take(256 * 512 * 2);
  h16* W2T = (h16*)take(512 * 512 * 2);
  h16* W3T = (h16*)take(512 * 512 * 2);
  h16* Wh1T = (h16*)take(512 * 512 * 2);
  h16* Wh2T = (h16*)take(512 * 512 * 2);
  h16* Wc1T = (h16*)take(512 * 512 * 2);
  h16* Wc2T = (h16*)take(512 * 512 * 2);
  h16* Wx1T = (h16*)take(512 * 512 * 2);
  h16* Wx2T = (h16*)take(128 * 512 * 2);
  h16* WpT = (h16*)take(128 * 512 * 2);
  h16* WgT = (h16*)take((size_t)2048 * 640 * 2);
  float* bg = (float*)take(2048 * 4);
  unsigned int* hcnt = (unsigned int*)take((size_t)TT * 32 * 4);

  (void)hipMemsetAsync(hcnt, 0, (size_t)TT * 32 * 4, stream);

  dim3 blk(256);
  cvt16<<<(BB * 256 + 255) / 256, blk, 0, stream>>>(x, X16, BB * 256);
  transposeW<<<(256 * 512 + 255) / 256, blk, 0, stream>>>(W1, W1T, 256, 512);
  transposeW<<<(512 * 512 + 255) / 256, blk, 0, stream>>>(W2, W2T, 512, 512);
  transposeW<<<(512 * 512 + 255) / 256, blk, 0, stream>>>(W3, W3T, 512, 512);
  transposeW<<<(512 * 512 + 255) / 256, blk, 0, stream>>>(Wh1, Wh1T, 512, 512);
  transposeW<<<(512 * 512 + 255) / 256, blk, 0, stream>>>(Wh2, Wh2T, 512, 512);
  transposeW<<<(512 * 512 + 255) / 256, blk, 0, stream>>>(Wc1, Wc1T, 512, 512);
  transposeW<<<(512 * 512 + 255) / 256, blk, 0, stream>>>(Wc2, Wc2T, 512, 512);
  transposeW<<<(512 * 512 + 255) / 256, blk, 0, stream>>>(Wx1, Wx1T, 512, 512);
  transposeW<<<(512 * 128 + 255) / 256, blk, 0, stream>>>(Wx2, Wx2T, 512, 128);
  transposeW<<<(512 * 128 + 255) / 256, blk, 0, stream>>>(Wp, WpT, 512, 128);
  prep_gate<<<(2048 * 640 + 255) / 256, blk, 0, stream>>>(Wih, Whh, bih, bhh, WgT, bg);

  // MLP encoder
  gemm128<EP_LRELU><<<dim3(64, 4), blk, 0, stream>>>(X16, 256, W1T, b1, 256, Za, 512, 0, nullptr, 0);
  gemm128<EP_LRELU><<<dim3(64, 4), blk, 0, stream>>>(Za, 512, W2T, b2, 512, Zb, 512, 0, nullptr, 0);
  gemm128<EP_LRELU><<<dim3(64, 4), blk, 0, stream>>>(Zb, 512, W3T, b3, 512, Za, 512, 0, nullptr, 0);
  gemm128<EP_LRELU><<<dim3(64, 4), blk, 0, stream>>>(Za, 512, Wh1T, bh1, 512, Zb, 512, 0, nullptr, 0);
  gemm128<EP_LIN16><<<dim3(64, 4), blk, 0, stream>>>(Zb, 512, Wh2T, bh2, 512, XHa, 640, 128, nullptr, 0);
  gemm128<EP_LRELU><<<dim3(64, 4), blk, 0, stream>>>(Za, 512, Wc1T, bc1, 512, Zb, 512, 0, nullptr, 0);
  gemm128<EP_F32><<<dim3(64, 4), blk, 0, stream>>>(Zb, 512, Wc2T, bc2, 512, nullptr, 0, 0, C, 512);
  gemm128<EP_LRELU><<<dim3(64, 4), blk, 0, stream>>>(Za, 512, Wx1T, bx1, 512, Zb, 512, 0, nullptr, 0);
  head_gemm2<<<128, blk, 0, stream>>>(Zb, 512, Wx2T, bx2, 8, XHa, nullptr, 0);

  // LSTM decoder: one fused kernel per step (gate + cell + last-arriver head)
  float* yout = (float*)d_out;
  for (int t = 0; t < TT; ++t) {
    h16* in_ = (t & 1) ? XHb : XHa;
    h16* out_ = (t & 1) ? XHa : XHb;
    gate8<<<dim3(32, 8), dim3(512), 0, stream>>>(in_, WgT, bg, C, out_, WpT, bp,
                                                 yout, t, hcnt + t * 32);
  }
}

// Round 6
// 4576.740 us; speedup vs baseline: 1.2556x; 1.0798x over previous
//
#include <hip/hip_runtime.h>

// ---------------------------------------------------------------------------
// LinearDecoder: MLP encoder -> 64-step LSTM decoder with softmax/sigmoid head
// B=8192, LAT=256, MLP=512, HID=512, INP=128, T=64, gates N=2048, K=640
// Decoder: one kernel/step. Each block FIRST computes head(h(t)) for its own
// 256 rows (redundant across the 8 n-blocks -> no cross-block dependency),
// writes x(t), drains, then runs the verified 8-phase 256x256 gate GEMM.
// ---------------------------------------------------------------------------

typedef _Float16 h16;
typedef __attribute__((ext_vector_type(8))) _Float16 f16x8;
typedef __attribute__((ext_vector_type(4))) float f32x4;

#define BB 8192
#define TT 64

__device__ __forceinline__ void gload16(const void* g, void* lds) {
  __builtin_amdgcn_global_load_lds(
      (const __attribute__((address_space(1))) unsigned int*)g,
      (__attribute__((address_space(3))) unsigned int*)lds, 16, 0, 0);
}

__device__ __forceinline__ float sigm(float x) { return 1.f / (1.f + __expf(-x)); }
__device__ __forceinline__ float tanhf_(float x) { return 2.f / (1.f + __expf(-2.f * x)) - 1.f; }

#define MIDBAR_LG()                                        \
  do {                                                     \
    __builtin_amdgcn_s_barrier();                          \
    asm volatile("s_waitcnt lgkmcnt(0)" ::: "memory");     \
    __builtin_amdgcn_sched_barrier(0);                     \
  } while (0)
#define ENDBAR()                                           \
  do {                                                     \
    __builtin_amdgcn_s_barrier();                          \
    asm volatile("" ::: "memory");                         \
  } while (0)

// ---------------------------------------------------------------------------
// Fused decoder step kernel.
//   Phase H (tstep>0): head(h(t)) for own 256 rows -> x(t) into Ain x-part,
//                      y[tstep-1] (ny==0 only). 8x redundant across n-blocks.
//   Phase G: 8-phase 256x256 gate GEMM (verified R2 schedule) + LSTM cell.
// Gate col permutation: n' = by*256 + wc*64 + q*16 + jj
//                       orig = q*512 + (by*64 + wc*16 + jj)
// ---------------------------------------------------------------------------
__global__ __launch_bounds__(512, 2) void gate8(
    h16* __restrict__ Ain, const h16* __restrict__ Bt,
    const float* __restrict__ bg, float* __restrict__ Cbuf,
    h16* __restrict__ Hout, const h16* __restrict__ WpT,
    const float* __restrict__ bp, float* __restrict__ yout, int tstep) {
  __shared__ __align__(16) h16 As[2][16384];
  __shared__ __align__(16) h16 Bs[2][16384];
  const int tid = threadIdx.x;
  const int lane = tid & 63;
  const int wid = tid >> 6;
  const int wr = wid >> 2, wc = wid & 3;
  const int m0 = blockIdx.x * 256;
  const int n0 = blockIdx.y * 256;
  const int arow = lane & 15, khi = lane >> 4;
  const int x7 = arow & 7;

  // ================= Phase H: redundant head for own rows =================
  if (tstep > 0) {
    h16* Hlds = (h16*)As;     // [128][256] = 64KB
    h16* Wlds = (h16*)Bs;     // [128][256] = 64KB
    const bool doY = (blockIdx.y == 0);
    f32x4 ha[2][8];
#pragma unroll 1
    for (int kh = 0; kh < 2; ++kh) {
      // stage Wp K-half: 128 rows x 256 cols
#pragma unroll
      for (int li = 0; li < 8; ++li) {
        int L = wid * 8 + li;
        int row = 2 * L + (lane >> 5);
        int gcc = (lane & 31) ^ (row & 7);
        gload16(WpT + (size_t)row * 512 + kh * 256 + gcc * 8, &Wlds[(2 * L) * 256]);
      }
#pragma unroll 1
      for (int rh2 = 0; rh2 < 2; ++rh2) {
        // stage h rows [m0+rh2*128, +128), K-half kh  (h = Ain cols 128..640)
#pragma unroll
        for (int li = 0; li < 8; ++li) {
          int L = wid * 8 + li;
          int row = 2 * L + (lane >> 5);
          int gcc = (lane & 31) ^ (row & 7);
          gload16(Ain + (size_t)(m0 + rh2 * 128 + row) * 640 + 128 + kh * 256 + gcc * 8,
                  &Hlds[(2 * L) * 256]);
        }
        asm volatile("s_waitcnt vmcnt(0)" ::: "memory");
        __builtin_amdgcn_s_barrier();
        if (kh == 0) {
#pragma unroll
          for (int nt = 0; nt < 8; ++nt) ha[rh2][nt] = (f32x4)0.f;
        }
        int ra = wid * 16 + arow;
#pragma unroll
        for (int ks = 0; ks < 8; ++ks) {
          f16x8 afr = *(const f16x8*)&Hlds[ra * 256 + ((ks * 4 + khi) ^ x7) * 8];
#pragma unroll
          for (int nt = 0; nt < 8; ++nt) {
            int rb = nt * 16 + arow;
            f16x8 bfr = *(const f16x8*)&Wlds[rb * 256 + ((ks * 4 + khi) ^ x7) * 8];
            ha[rh2][nt] =
                __builtin_amdgcn_mfma_f32_16x16x32_f16(afr, bfr, ha[rh2][nt], 0, 0, 0);
          }
        }
        __builtin_amdgcn_s_barrier();  // protect Hlds/Wlds before next stage
      }
    }
    // softmax / sigmoid + x/y writes
#pragma unroll
    for (int rh2 = 0; rh2 < 2; ++rh2) {
#pragma unroll
      for (int r = 0; r < 4; ++r) {
        int m = m0 + rh2 * 128 + wid * 16 + khi * 4 + r;
        float v[8];
        float mx = -1e30f;
#pragma unroll
        for (int nt = 0; nt < 8; ++nt) {
          int col = nt * 16 + arow;
          v[nt] = ha[rh2][nt][r] + bp[col];
          if (col != 127) mx = fmaxf(mx, v[nt]);
        }
#pragma unroll
        for (int s = 1; s < 16; s <<= 1) mx = fmaxf(mx, __shfl_xor(mx, s, 16));
        float sm = 0.f;
#pragma unroll
        for (int nt = 0; nt < 8; ++nt) {
          int col = nt * 16 + arow;
          if (col != 127) sm += __expf(v[nt] - mx);
        }
#pragma unroll
        for (int s = 1; s < 16; s <<= 1) sm += __shfl_xor(sm, s, 16);
        float inv = 1.f / sm;
#pragma unroll
        for (int nt = 0; nt < 8; ++nt) {
          int col = nt * 16 + arow;
          float res = (col == 127) ? sigm(v[nt]) : __expf(v[nt] - mx) * inv;
          Ain[(size_t)m * 640 + col] = (h16)res;
          if (doY) yout[((size_t)m * 64 + (tstep - 1)) * 128 + col] = res;
        }
      }
    }
    asm volatile("s_waitcnt vmcnt(0)" ::: "memory");  // x stores visible in L2
    __syncthreads();
  }

  // ================= Phase G: verified 8-phase gate GEMM =================
  auto stage = [&](h16(*dst)[16384], int slot, int h, const h16* src, int base,
                   int kt) {
#pragma unroll
    for (int li = 0; li < 2; ++li) {
      int rowbase = li * 128 + h * 64 + wid * 8;  // wave-uniform
      int row = rowbase + (lane >> 3);
      int gc = (lane & 7) ^ (lane >> 3);
      gload16(src + (size_t)(base + row) * 640 + kt * 64 + gc * 8,
              &dst[slot][rowbase * 64]);
    }
  };

  f32x4 acc[8][4];
#pragma unroll
  for (int i = 0; i < 8; ++i)
#pragma unroll
    for (int jj = 0; jj < 4; ++jj) acc[i][jj] = (f32x4)0.f;
  f16x8 af[4], bf[2][4];

  auto readA = [&](int slot, int ms, int ks) {
#pragma unroll
    for (int mr = 0; mr < 4; ++mr) {
      int r = wr * 128 + ms * 64 + mr * 16 + arow;
      af[mr] = *(const f16x8*)&As[slot][r * 64 + ((ks * 4 + khi) ^ x7) * 8];
    }
  };
  auto readB = [&](int slot, int ks) {
#pragma unroll
    for (int jj = 0; jj < 4; ++jj) {
      int rb = wc * 64 + jj * 16 + arow;
      bf[ks][jj] = *(const f16x8*)&Bs[slot][rb * 64 + ((ks * 4 + khi) ^ x7) * 8];
    }
  };
  auto mfma16 = [&](int ms, int ks) {
    __builtin_amdgcn_s_setprio(1);
#pragma unroll
    for (int mr = 0; mr < 4; ++mr)
#pragma unroll
      for (int jj = 0; jj < 4; ++jj)
        acc[ms * 4 + mr][jj] = __builtin_amdgcn_mfma_f32_16x16x32_f16(
            af[mr], bf[ks][jj], acc[ms * 4 + mr][jj], 0, 0, 0);
    __builtin_amdgcn_s_setprio(0);
  };

  // prologue: kt0 fully, kt1 all but A-h1
  stage(Bs, 0, 0, Bt, n0, 0);
  stage(Bs, 0, 1, Bt, n0, 0);
  stage(As, 0, 0, Ain, m0, 0);
  stage(As, 0, 1, Ain, m0, 0);
  stage(Bs, 1, 0, Bt, n0, 1);
  stage(Bs, 1, 1, Bt, n0, 1);
  stage(As, 1, 0, Ain, m0, 1);
  asm volatile("s_waitcnt vmcnt(6)" ::: "memory");
  ENDBAR();

#pragma unroll 1
  for (int i = 0; i < 5; ++i) {
    const int t2 = 2 * i + 2, t3 = 2 * i + 3;
    // P1
    readB(0, 0);
    readB(0, 1);
    readA(0, 0, 0);
    stage(As, 1, 1, Ain, m0, 2 * i + 1);
    MIDBAR_LG();
    mfma16(0, 0);
    ENDBAR();
    // P2
    readA(0, 0, 1);
    if (t2 < 10) stage(Bs, 0, 0, Bt, n0, t2);
    MIDBAR_LG();
    mfma16(0, 1);
    ENDBAR();
    // P3
    readA(0, 1, 0);
    if (t2 < 10) stage(Bs, 0, 1, Bt, n0, t2);
    MIDBAR_LG();
    mfma16(1, 0);
    ENDBAR();
    // P4
    readA(0, 1, 1);
    if (t2 < 10) stage(As, 0, 0, Ain, m0, t2);
    if (i < 4)
      asm volatile("s_waitcnt vmcnt(6)" ::: "memory");
    else
      asm volatile("s_waitcnt vmcnt(0)" ::: "memory");
    MIDBAR_LG();
    mfma16(1, 1);
    ENDBAR();
    // P5
    readB(1, 0);
    readB(1, 1);
    readA(1, 0, 0);
    if (t2 < 10) stage(As, 0, 1, Ain, m0, t2);
    MIDBAR_LG();
    mfma16(0, 0);
    ENDBAR();
    // P6
    readA(1, 0, 1);
    if (t3 < 10) stage(Bs, 1, 0, Bt, n0, t3);
    MIDBAR_LG();
    mfma16(0, 1);
    ENDBAR();
    // P7
    readA(1, 1, 0);
    if (t3 < 10) stage(Bs, 1, 1, Bt, n0, t3);
    MIDBAR_LG();
    mfma16(1, 0);
    ENDBAR();
    // P8
    readA(1, 1, 1);
    if (t3 < 10) stage(As, 1, 0, Ain, m0, t3);
    if (i < 4)
      asm volatile("s_waitcnt vmcnt(6)" ::: "memory");
    else
      asm volatile("s_waitcnt vmcnt(0)" ::: "memory");
    MIDBAR_LG();
    mfma16(1, 1);
    ENDBAR();
  }

  // ---- gate epilogue: LSTM cell update ----
  const int nb = n0 + wc * 64;
  const float bI = bg[nb + arow];
  const float bF = bg[nb + 16 + arow];
  const float bG = bg[nb + 32 + arow];
  const float bO = bg[nb + 48 + arow];
  const int hj = blockIdx.y * 64 + wc * 16 + arow;
#pragma unroll
  for (int mrep = 0; mrep < 8; ++mrep) {
#pragma unroll
    for (int r = 0; r < 4; ++r) {
      int m = m0 + wr * 128 + mrep * 16 + khi * 4 + r;
      float gi = sigm(acc[mrep][0][r] + bI);
      float gf = sigm(acc[mrep][1][r] + bF);
      float gg = tanhf_(acc[mrep][2][r] + bG);
      float go = sigm(acc[mrep][3][r] + bO);
      size_t ci = (size_t)m * 512 + hj;
      float c2 = gf * Cbuf[ci] + gi * gg;
      Cbuf[ci] = c2;
      Hout[(size_t)m * 640 + 128 + hj] = (h16)(go * tanhf_(c2));
    }
  }
}

// ---------------------------------------------------------------------------
// Head GEMM (encoder x0 + final y[63]) — verified round-2 structure
// ---------------------------------------------------------------------------
__global__ __launch_bounds__(256) void head_gemm2(
    const h16* __restrict__ A, int lda, const h16* __restrict__ Bt,
    const float* __restrict__ bias, int nkt, h16* __restrict__ Xout,
    float* __restrict__ ydst, int tstep) {
  __shared__ __align__(16) h16 As[2][64 * 64];
  __shared__ __align__(16) h16 Bs[2][128 * 64];
  const int tid = threadIdx.x;
  const int lane = tid & 63;
  const int w = tid >> 6;
  const int m0 = blockIdx.x * 64;
  const int arow = lane & 15, khi = lane >> 4;
  const int x7 = arow & 7;

  auto stageA = [&](int slot, int kt) {
#pragma unroll
    for (int li = 0; li < 2; ++li) {
      int rowbase = li * 32 + w * 8;
      int row = rowbase + (lane >> 3);
      int gc = (lane & 7) ^ (lane >> 3);
      gload16(A + (size_t)(m0 + row) * lda + kt * 64 + gc * 8,
              &As[slot][rowbase * 64]);
    }
  };
  auto stageB = [&](int slot, int kt) {
#pragma unroll
    for (int li = 0; li < 4; ++li) {
      int rowbase = li * 32 + w * 8;
      int row = rowbase + (lane >> 3);
      int gc = (lane & 7) ^ (lane >> 3);
      gload16(Bt + (size_t)row * 512 + kt * 64 + gc * 8, &Bs[slot][rowbase * 64]);
    }
  };

  f32x4 acc[8];
#pragma unroll
  for (int jj = 0; jj < 8; ++jj) acc[jj] = (f32x4)0.f;

  stageA(0, 0);
  stageB(0, 0);
#pragma unroll 1
  for (int kt = 0; kt < nkt; ++kt) {
    int p = kt & 1;
    if (kt + 1 < nkt) {
      stageA(p ^ 1, kt + 1);
      stageB(p ^ 1, kt + 1);
      asm volatile("s_waitcnt vmcnt(6)" ::: "memory");
    } else {
      asm volatile("s_waitcnt vmcnt(0)" ::: "memory");
    }
    ENDBAR();
#pragma unroll
    for (int kk = 0; kk < 2; ++kk) {
      int kc = kk * 4 + khi;
      int ra = w * 16 + arow;
      f16x8 afr = *(const f16x8*)&As[p][ra * 64 + (kc ^ x7) * 8];
#pragma unroll
      for (int nt = 0; nt < 8; ++nt) {
        int rb = nt * 16 + arow;
        f16x8 bfr = *(const f16x8*)&Bs[p][rb * 64 + (kc ^ x7) * 8];
        acc[nt] = __builtin_amdgcn_mfma_f32_16x16x32_f16(afr, bfr, acc[nt], 0, 0, 0);
      }
    }
    ENDBAR();
  }

#pragma unroll
  for (int r = 0; r < 4; ++r) {
    int m = m0 + w * 16 + khi * 4 + r;
    float v[8];
    float mx = -1e30f;
#pragma unroll
    for (int nt = 0; nt < 8; ++nt) {
      int col = nt * 16 + arow;
      v[nt] = acc[nt][r] + bias[col];
      if (col != 127) mx = fmaxf(mx, v[nt]);
    }
#pragma unroll
    for (int s = 1; s < 16; s <<= 1) mx = fmaxf(mx, __shfl_xor(mx, s, 16));
    float sm = 0.f;
#pragma unroll
    for (int nt = 0; nt < 8; ++nt) {
      int col = nt * 16 + arow;
      if (col != 127) sm += __expf(v[nt] - mx);
    }
#pragma unroll
    for (int s = 1; s < 16; s <<= 1) sm += __shfl_xor(sm, s, 16);
    float inv = 1.f / sm;
#pragma unroll
    for (int nt = 0; nt < 8; ++nt) {
      int col = nt * 16 + arow;
      float res = (col == 127) ? sigm(v[nt]) : __expf(v[nt] - mx) * inv;
      Xout[(size_t)m * 640 + col] = (h16)res;
      if (ydst) ydst[((size_t)m * 64 + tstep) * 128 + col] = res;
    }
  }
}

// ---------------------------------------------------------------------------
// Encoder GEMM (verified round-1 structure, 128x128 tile)
// ---------------------------------------------------------------------------
enum { EP_LRELU = 0, EP_LIN16 = 1, EP_F32 = 2 };

template <int EP>
__global__ __launch_bounds__(256) void gemm128(
    const h16* __restrict__ A, int lda, const h16* __restrict__ Bt,
    const float* __restrict__ bias, int K, h16* __restrict__ out16, int ldo,
    int ocol, float* __restrict__ outf, int ldf) {
  __shared__ __align__(16) h16 As[128 * 64];
  __shared__ __align__(16) h16 Bs[128 * 64];
  const int tid = threadIdx.x;
  const int lane = tid & 63;
  const int w = tid >> 6;
  const int m0 = blockIdx.x * 128;
  const int n0 = blockIdx.y * 128;

  f32x4 acc[4][4];
#pragma unroll
  for (int i = 0; i < 4; ++i)
#pragma unroll
    for (int jj = 0; jj < 4; ++jj) acc[i][jj] = (f32x4)0.f;

  const int rh = (w >> 1) * 64;
  const int arow = lane & 15;
  const int khi = lane >> 4;

  const int nkt = K >> 6;
  for (int kt = 0; kt < nkt; ++kt) {
#pragma unroll
    for (int li = 0; li < 4; ++li) {
      int L = w * 4 + li;
      int r = L * 8 + (lane >> 3);
      int c = lane & 7;
      int gc = c ^ (r & 7);
      gload16(A + (size_t)(m0 + r) * lda + kt * 64 + gc * 8, &As[L * 512]);
      gload16(Bt + (size_t)(n0 + r) * K + kt * 64 + gc * 8, &Bs[L * 512]);
    }
    __syncthreads();
#pragma unroll
    for (int kk = 0; kk < 2; ++kk) {
      const int kc = kk * 4 + khi;
      f16x8 af[4], bf[4];
#pragma unroll
      for (int mt = 0; mt < 4; ++mt) {
        int r = rh + mt * 16 + arow;
        af[mt] = *(const f16x8*)&As[r * 64 + (kc ^ (r & 7)) * 8];
      }
#pragma unroll
      for (int jj = 0; jj < 4; ++jj) {
        int nt = (w & 1) * 4 + jj;
        int r = nt * 16 + arow;
        bf[jj] = *(const f16x8*)&Bs[r * 64 + (kc ^ (r & 7)) * 8];
      }
#pragma unroll
      for (int mt = 0; mt < 4; ++mt)
#pragma unroll
        for (int jj = 0; jj < 4; ++jj)
          acc[mt][jj] =
              __builtin_amdgcn_mfma_f32_16x16x32_f16(af[mt], bf[jj], acc[mt][jj], 0, 0, 0);
    }
    __syncthreads();
  }

#pragma unroll
  for (int mt = 0; mt < 4; ++mt) {
#pragma unroll
    for (int jj = 0; jj < 4; ++jj) {
      int nt = (w & 1) * 4 + jj;
      int n = n0 + nt * 16 + arow;
      float bv = bias[n];
#pragma unroll
      for (int r = 0; r < 4; ++r) {
        int m = m0 + rh + mt * 16 + khi * 4 + r;
        float v = acc[mt][jj][r] + bv;
        if constexpr (EP == EP_LRELU) {
          v = v >= 0.f ? v : 0.2f * v;
          out16[(size_t)m * ldo + n] = (h16)v;
        } else if constexpr (EP == EP_LIN16) {
          out16[(size_t)m * ldo + ocol + n] = (h16)v;
        } else {
          outf[(size_t)m * ldf + n] = v;
        }
      }
    }
  }
}

// ---------------- prep kernels ----------------
__global__ void cvt16(const float* __restrict__ in, h16* __restrict__ out, int n) {
  int i = blockIdx.x * 256 + threadIdx.x;
  if (i < n) out[i] = (h16)in[i];
}

__global__ void transposeW(const float* __restrict__ W, h16* __restrict__ WT, int K,
                           int N) {
  int i = blockIdx.x * 256 + threadIdx.x;
  if (i >= K * N) return;
  int k = i / N, n = i % N;
  WT[(size_t)n * K + k] = (h16)W[i];
}

// WgT[n'][640]: n' = by*256 + wc*64 + q*16 + jj -> orig = q*512 + by*64 + wc*16 + jj
__global__ void prep_gate(const float* __restrict__ Wih, const float* __restrict__ Whh,
                          const float* __restrict__ bih, const float* __restrict__ bhh,
                          h16* __restrict__ WgT, float* __restrict__ bg) {
  int i = blockIdx.x * 256 + threadIdx.x;
  if (i >= 2048 * 640) return;
  int np = i / 640, k = i % 640;
  int by = np >> 8, wcc = (np >> 6) & 3, q = (np >> 4) & 3, jj = np & 15;
  int orig = q * 512 + by * 64 + wcc * 16 + jj;
  float wv = (k < 128) ? Wih[(size_t)k * 2048 + orig]
                       : Whh[(size_t)(k - 128) * 2048 + orig];
  WgT[i] = (h16)wv;
  if (k == 0) bg[np] = bih[orig] + bhh[orig];
}

// ---------------- launch ----------------
extern "C" void kernel_launch(void* const* d_in, const int* in_sizes, int n_in,
                              void* d_out, int out_size, void* d_ws, size_t ws_size,
                              hipStream_t stream) {
  const float* x = (const float*)d_in[0];
  const float* W1 = (const float*)d_in[1];
  const float* b1 = (const float*)d_in[2];
  const float* W2 = (const float*)d_in[3];
  const float* b2 = (const float*)d_in[4];
  const float* W3 = (const float*)d_in[5];
  const float* b3 = (const float*)d_in[6];
  const float* Wh1 = (const float*)d_in[7];
  const float* bh1 = (const float*)d_in[8];
  const float* Wh2 = (const float*)d_in[9];
  const float* bh2 = (const float*)d_in[10];
  const float* Wc1 = (const float*)d_in[11];
  const float* bc1 = (const float*)d_in[12];
  const float* Wc2 = (const float*)d_in[13];
  const float* bc2 = (const float*)d_in[14];
  const float* Wx1 = (const float*)d_in[15];
  const float* bx1 = (const float*)d_in[16];
  const float* Wx2 = (const float*)d_in[17];
  const float* bx2 = (const float*)d_in[18];
  const float* Wih = (const float*)d_in[19];
  const float* bih = (const float*)d_in[20];
  const float* Whh = (const float*)d_in[21];
  const float* bhh = (const float*)d_in[22];
  const float* Wp = (const float*)d_in[23];
  const float* bp = (const float*)d_in[24];

  char* ws = (char*)d_ws;
  size_t off = 0;
  auto take = [&](size_t bytes) -> void* {
    void* p = ws + off;
    off += (bytes + 255) & ~(size_t)255;
    return p;
  };
  h16* X16 = (h16*)take((size_t)BB * 256 * 2);
  h16* Za = (h16*)take((size_t)BB * 512 * 2);
  h16* Zb = (h16*)take((size_t)BB * 512 * 2);
  h16* XHa = (h16*)take((size_t)BB * 640 * 2);
  h16* XHb = (h16*)take((size_t)BB * 640 * 2);
  float* C = (float*)take((size_t)BB * 512 * 4);
  h16* W1T = (h16*)take(256 * 512 * 2);
  h16* W2T = (h16*)take(512 * 512 * 2);
  h16* W3T = (h16*)take(512 * 512 * 2);
  h16* Wh1T = (h16*)take(512 * 512 * 2);
  h16* Wh2T = (h16*)take(512 * 512 * 2);
  h16* Wc1T = (h16*)take(512 * 512 * 2);
  h16* Wc2T = (h16*)take(512 * 512 * 2);
  h16* Wx1T = (h16*)take(512 * 512 * 2);
  h16* Wx2T = (h16*)take(128 * 512 * 2);
  h16* WpT = (h16*)take(128 * 512 * 2);
  h16* WgT = (h16*)take((size_t)2048 * 640 * 2);
  float* bg = (float*)take(2048 * 4);

  dim3 blk(256);
  cvt16<<<(BB * 256 + 255) / 256, blk, 0, stream>>>(x, X16, BB * 256);
  transposeW<<<(256 * 512 + 255) / 256, blk, 0, stream>>>(W1, W1T, 256, 512);
  transposeW<<<(512 * 512 + 255) / 256, blk, 0, stream>>>(W2, W2T, 512, 512);
  transposeW<<<(512 * 512 + 255) / 256, blk, 0, stream>>>(W3, W3T, 512, 512);
  transposeW<<<(512 * 512 + 255) / 256, blk, 0, stream>>>(Wh1, Wh1T, 512, 512);
  transposeW<<<(512 * 512 + 255) / 256, blk, 0, stream>>>(Wh2, Wh2T, 512, 512);
  transposeW<<<(512 * 512 + 255) / 256, blk, 0, stream>>>(Wc1, Wc1T, 512, 512);
  transposeW<<<(512 * 512 + 255) / 256, blk, 0, stream>>>(Wc2, Wc2T, 512, 512);
  transposeW<<<(512 * 512 + 255) / 256, blk, 0, stream>>>(Wx1, Wx1T, 512, 512);
  transposeW<<<(512 * 128 + 255) / 256, blk, 0, stream>>>(Wx2, Wx2T, 512, 128);
  transposeW<<<(512 * 128 + 255) / 256, blk, 0, stream>>>(Wp, WpT, 512, 128);
  prep_gate<<<(2048 * 640 + 255) / 256, blk, 0, stream>>>(Wih, Whh, bih, bhh, WgT, bg);

  // MLP encoder
  gemm128<EP_LRELU><<<dim3(64, 4), blk, 0, stream>>>(X16, 256, W1T, b1, 256, Za, 512, 0, nullptr, 0);
  gemm128<EP_LRELU><<<dim3(64, 4), blk, 0, stream>>>(Za, 512, W2T, b2, 512, Zb, 512, 0, nullptr, 0);
  gemm128<EP_LRELU><<<dim3(64, 4), blk, 0, stream>>>(Zb, 512, W3T, b3, 512, Za, 512, 0, nullptr, 0);
  gemm128<EP_LRELU><<<dim3(64, 4), blk, 0, stream>>>(Za, 512, Wh1T, bh1, 512, Zb, 512, 0, nullptr, 0);
  gemm128<EP_LIN16><<<dim3(64, 4), blk, 0, stream>>>(Zb, 512, Wh2T, bh2, 512, XHa, 640, 128, nullptr, 0);
  gemm128<EP_LRELU><<<dim3(64, 4), blk, 0, stream>>>(Za, 512, Wc1T, bc1, 512, Zb, 512, 0, nullptr, 0);
  gemm128<EP_F32><<<dim3(64, 4), blk, 0, stream>>>(Zb, 512, Wc2T, bc2, 512, nullptr, 0, 0, C, 512);
  gemm128<EP_LRELU><<<dim3(64, 4), blk, 0, stream>>>(Za, 512, Wx1T, bx1, 512, Zb, 512, 0, nullptr, 0);
  head_gemm2<<<128, blk, 0, stream>>>(Zb, 512, Wx2T, bx2, 8, XHa, nullptr, 0);

  // LSTM decoder: one fused kernel per step (redundant head + gate + cell)
  float* yout = (float*)d_out;
  for (int t = 0; t < TT; ++t) {
    h16* in_ = (t & 1) ? XHb : XHa;
    h16* out_ = (t & 1) ? XHa : XHb;
    gate8<<<dim3(32, 8), dim3(512), 0, stream>>>(in_, WgT, bg, C, out_, WpT, bp,
                                                 yout, t);
  }
  // final y[63] = head(h(64)); h(64) lives in XHa (t=63 odd -> out_=XHa)
  head_gemm2<<<128, blk, 0, stream>>>(XHa + 128, 640, WpT, bp, 8, XHa, yout, 63);
}

// Round 7
// 4507.912 us; speedup vs baseline: 1.2747x; 1.0153x over previous
//
#include <hip/hip_runtime.h>

// ---------------------------------------------------------------------------
// LinearDecoder: MLP encoder -> 64-step LSTM decoder with softmax/sigmoid head
// B=8192, LAT=256, MLP=512, HID=512, INP=128, T=64, gates N=2048, K=640
// Decoder: one kernel/step. Each block computes head(h(t)) for its own 256
// rows (redundant across n-blocks) and writes x(t) DIRECTLY into its LDS
// A-staging buffers (kt0/kt1 of K) -- x never goes to global (no cross-XCD
// write sharing). y written by ny==0 only. Gate = verified R2 8-phase GEMM.
// ---------------------------------------------------------------------------

typedef _Float16 h16;
typedef __attribute__((ext_vector_type(8))) _Float16 f16x8;
typedef __attribute__((ext_vector_type(4))) float f32x4;

#define BB 8192
#define TT 64

__device__ __forceinline__ void gload16(const void* g, void* lds) {
  __builtin_amdgcn_global_load_lds(
      (const __attribute__((address_space(1))) unsigned int*)g,
      (__attribute__((address_space(3))) unsigned int*)lds, 16, 0, 0);
}

__device__ __forceinline__ float sigm(float x) { return 1.f / (1.f + __expf(-x)); }
__device__ __forceinline__ float tanhf_(float x) { return 2.f / (1.f + __expf(-2.f * x)) - 1.f; }

#define MIDBAR_LG()                                        \
  do {                                                     \
    __builtin_amdgcn_s_barrier();                          \
    asm volatile("s_waitcnt lgkmcnt(0)" ::: "memory");     \
    __builtin_amdgcn_sched_barrier(0);                     \
  } while (0)
#define ENDBAR()                                           \
  do {                                                     \
    __builtin_amdgcn_s_barrier();                          \
    asm volatile("" ::: "memory");                         \
  } while (0)

// ---------------------------------------------------------------------------
// Fused decoder step kernel.
//   Phase H (tstep>0): head(h(t)) for own 256 rows; x -> LDS As prefill
//                      (swizzled fragment layout); y[tstep-1] by ny==0 only.
//   Phase G: 8-phase 256x256 gate GEMM (R2 schedule) + LSTM cell update.
// Gate col permutation: n' = by*256 + wc*64 + q*16 + jj
//                       orig = q*512 + (by*64 + wc*16 + jj)
// ---------------------------------------------------------------------------
__global__ __launch_bounds__(512, 2) void gate8(
    const h16* __restrict__ Ain, const h16* __restrict__ Bt,
    const float* __restrict__ bg, float* __restrict__ Cbuf,
    h16* __restrict__ Hout, const h16* __restrict__ WpT,
    const float* __restrict__ bp, float* __restrict__ yout, int tstep) {
  __shared__ __align__(16) h16 As[2][16384];
  __shared__ __align__(16) h16 Bs[2][16384];
  const int tid = threadIdx.x;
  const int lane = tid & 63;
  const int wid = tid >> 6;
  const int wr = wid >> 2, wc = wid & 3;
  const int m0 = blockIdx.x * 256;
  const int n0 = blockIdx.y * 256;
  const int arow = lane & 15, khi = lane >> 4;
  const int x7 = arow & 7;

  // ================= Phase H: redundant head -> LDS x prefill =============
  if (tstep > 0) {
    h16* Hlds = (h16*)As;    // [128][256] = 64KB
    h16* Wlds = (h16*)Bs;    // [128][256] = 64KB
    const bool doY = (blockIdx.y == 0);
    f32x4 ha[2][8];
#pragma unroll 1
    for (int kh = 0; kh < 2; ++kh) {
      // stage Wp K-half: 128 rows x 256 cols
#pragma unroll
      for (int li = 0; li < 8; ++li) {
        int L = wid * 8 + li;
        int row = 2 * L + (lane >> 5);
        int gcc = (lane & 31) ^ (row & 7);
        gload16(WpT + (size_t)row * 512 + kh * 256 + gcc * 8, &Wlds[(2 * L) * 256]);
      }
#pragma unroll 1
      for (int rh2 = 0; rh2 < 2; ++rh2) {
        // stage h rows [m0+rh2*128, +128), K-half kh  (h = Ain cols 128..640)
#pragma unroll
        for (int li = 0; li < 8; ++li) {
          int L = wid * 8 + li;
          int row = 2 * L + (lane >> 5);
          int gcc = (lane & 31) ^ (row & 7);
          gload16(Ain + (size_t)(m0 + rh2 * 128 + row) * 640 + 128 + kh * 256 + gcc * 8,
                  &Hlds[(2 * L) * 256]);
        }
        asm volatile("s_waitcnt vmcnt(0)" ::: "memory");
        __builtin_amdgcn_s_barrier();
        if (kh == 0) {
#pragma unroll
          for (int nt = 0; nt < 8; ++nt) ha[rh2][nt] = (f32x4)0.f;
        }
        int ra = wid * 16 + arow;
#pragma unroll
        for (int ks = 0; ks < 8; ++ks) {
          f16x8 afr = *(const f16x8*)&Hlds[ra * 256 + ((ks * 4 + khi) ^ x7) * 8];
#pragma unroll
          for (int nt = 0; nt < 8; ++nt) {
            int rb = nt * 16 + arow;
            f16x8 bfr = *(const f16x8*)&Wlds[rb * 256 + ((ks * 4 + khi) ^ x7) * 8];
            ha[rh2][nt] =
                __builtin_amdgcn_mfma_f32_16x16x32_f16(afr, bfr, ha[rh2][nt], 0, 0, 0);
          }
        }
        __builtin_amdgcn_s_barrier();  // protect Hlds/Wlds before next stage
      }
    }
    // softmax / sigmoid -> LDS As prefill (+ y by ny==0)
#pragma unroll
    for (int rh2 = 0; rh2 < 2; ++rh2) {
#pragma unroll
      for (int r = 0; r < 4; ++r) {
        int m_rel = rh2 * 128 + wid * 16 + khi * 4 + r;
        float v[8];
        float mx = -1e30f;
#pragma unroll
        for (int nt = 0; nt < 8; ++nt) {
          int col = nt * 16 + arow;
          v[nt] = ha[rh2][nt][r] + bp[col];
          if (col != 127) mx = fmaxf(mx, v[nt]);
        }
#pragma unroll
        for (int s = 1; s < 16; s <<= 1) mx = fmaxf(mx, __shfl_xor(mx, s, 16));
        float sm = 0.f;
#pragma unroll
        for (int nt = 0; nt < 8; ++nt) {
          int col = nt * 16 + arow;
          if (col != 127) sm += __expf(v[nt] - mx);
        }
#pragma unroll
        for (int s = 1; s < 16; s <<= 1) sm += __shfl_xor(sm, s, 16);
        float inv = 1.f / sm;
#pragma unroll
        for (int nt = 0; nt < 8; ++nt) {
          int col = nt * 16 + arow;
          float res = (col == 127) ? sigm(v[nt]) : __expf(v[nt] - mx) * inv;
          // x -> As prefill: slot = col>>6, cc = col&63, global chunk cc>>3
          int slot = col >> 6, cc = col & 63;
          As[slot][m_rel * 64 + (((cc >> 3) ^ (m_rel & 7)) << 3) + (cc & 7)] =
              (h16)res;
          if (doY) yout[((size_t)(m0 + m_rel) * 64 + (tstep - 1)) * 128 + col] = res;
        }
      }
    }
    asm volatile("s_waitcnt lgkmcnt(0)" ::: "memory");
    __syncthreads();
  }

  // ================= Phase G: verified 8-phase gate GEMM =================
  auto stage = [&](h16(*dst)[16384], int slot, int h, const h16* src, int base,
                   int kt) {
#pragma unroll
    for (int li = 0; li < 2; ++li) {
      int rowbase = li * 128 + h * 64 + wid * 8;  // wave-uniform
      int row = rowbase + (lane >> 3);
      int gc = (lane & 7) ^ (lane >> 3);
      gload16(src + (size_t)(base + row) * 640 + kt * 64 + gc * 8,
              &dst[slot][rowbase * 64]);
    }
  };

  f32x4 acc[8][4];
#pragma unroll
  for (int i = 0; i < 8; ++i)
#pragma unroll
    for (int jj = 0; jj < 4; ++jj) acc[i][jj] = (f32x4)0.f;
  f16x8 af[4], bf[2][4];

  auto readA = [&](int slot, int ms, int ks) {
#pragma unroll
    for (int mr = 0; mr < 4; ++mr) {
      int r = wr * 128 + ms * 64 + mr * 16 + arow;
      af[mr] = *(const f16x8*)&As[slot][r * 64 + ((ks * 4 + khi) ^ x7) * 8];
    }
  };
  auto readB = [&](int slot, int ks) {
#pragma unroll
    for (int jj = 0; jj < 4; ++jj) {
      int rb = wc * 64 + jj * 16 + arow;
      bf[ks][jj] = *(const f16x8*)&Bs[slot][rb * 64 + ((ks * 4 + khi) ^ x7) * 8];
    }
  };
  auto mfma16 = [&](int ms, int ks) {
    __builtin_amdgcn_s_setprio(1);
#pragma unroll
    for (int mr = 0; mr < 4; ++mr)
#pragma unroll
      for (int jj = 0; jj < 4; ++jj)
        acc[ms * 4 + mr][jj] = __builtin_amdgcn_mfma_f32_16x16x32_f16(
            af[mr], bf[ks][jj], acc[ms * 4 + mr][jj], 0, 0, 0);
    __builtin_amdgcn_s_setprio(0);
  };

  if (tstep == 0) {
    // full prologue: kt0 fully, kt1 all but A-h1 (x comes from global)
    stage(Bs, 0, 0, Bt, n0, 0);
    stage(Bs, 0, 1, Bt, n0, 0);
    stage(As, 0, 0, Ain, m0, 0);
    stage(As, 0, 1, Ain, m0, 0);
    stage(Bs, 1, 0, Bt, n0, 1);
    stage(Bs, 1, 1, Bt, n0, 1);
    stage(As, 1, 0, Ain, m0, 1);
    asm volatile("s_waitcnt vmcnt(6)" ::: "memory");
  } else {
    // As kt0/kt1 prefilled from phase H; stage only B
    stage(Bs, 0, 0, Bt, n0, 0);
    stage(Bs, 0, 1, Bt, n0, 0);
    stage(Bs, 1, 0, Bt, n0, 1);
    stage(Bs, 1, 1, Bt, n0, 1);
    asm volatile("s_waitcnt vmcnt(4)" ::: "memory");
  }
  ENDBAR();

#pragma unroll 1
  for (int i = 0; i < 5; ++i) {
    const int t2 = 2 * i + 2, t3 = 2 * i + 3;
    // P1
    readB(0, 0);
    readB(0, 1);
    readA(0, 0, 0);
    if (i > 0 || tstep == 0) stage(As, 1, 1, Ain, m0, 2 * i + 1);
    MIDBAR_LG();
    mfma16(0, 0);
    ENDBAR();
    // P2
    readA(0, 0, 1);
    if (t2 < 10) stage(Bs, 0, 0, Bt, n0, t2);
    MIDBAR_LG();
    mfma16(0, 1);
    ENDBAR();
    // P3
    readA(0, 1, 0);
    if (t2 < 10) stage(Bs, 0, 1, Bt, n0, t2);
    MIDBAR_LG();
    mfma16(1, 0);
    ENDBAR();
    // P4
    readA(0, 1, 1);
    if (t2 < 10) stage(As, 0, 0, Ain, m0, t2);
    if (i < 4)
      asm volatile("s_waitcnt vmcnt(6)" ::: "memory");
    else
      asm volatile("s_waitcnt vmcnt(0)" ::: "memory");
    MIDBAR_LG();
    mfma16(1, 1);
    ENDBAR();
    // P5
    readB(1, 0);
    readB(1, 1);
    readA(1, 0, 0);
    if (t2 < 10) stage(As, 0, 1, Ain, m0, t2);
    MIDBAR_LG();
    mfma16(0, 0);
    ENDBAR();
    // P6
    readA(1, 0, 1);
    if (t3 < 10) stage(Bs, 1, 0, Bt, n0, t3);
    MIDBAR_LG();
    mfma16(0, 1);
    ENDBAR();
    // P7
    readA(1, 1, 0);
    if (t3 < 10) stage(Bs, 1, 1, Bt, n0, t3);
    MIDBAR_LG();
    mfma16(1, 0);
    ENDBAR();
    // P8
    readA(1, 1, 1);
    if (t3 < 10) stage(As, 1, 0, Ain, m0, t3);
    if (i < 4)
      asm volatile("s_waitcnt vmcnt(6)" ::: "memory");
    else
      asm volatile("s_waitcnt vmcnt(0)" ::: "memory");
    MIDBAR_LG();
    mfma16(1, 1);
    ENDBAR();
  }

  // ---- gate epilogue: LSTM cell update ----
  const int nb = n0 + wc * 64;
  const float bI = bg[nb + arow];
  const float bF = bg[nb + 16 + arow];
  const float bG = bg[nb + 32 + arow];
  const float bO = bg[nb + 48 + arow];
  const int hj = blockIdx.y * 64 + wc * 16 + arow;
#pragma unroll
  for (int mrep = 0; mrep < 8; ++mrep) {
#pragma unroll
    for (int r = 0; r < 4; ++r) {
      int m = m0 + wr * 128 + mrep * 16 + khi * 4 + r;
      float gi = sigm(acc[mrep][0][r] + bI);
      float gf = sigm(acc[mrep][1][r] + bF);
      float gg = tanhf_(acc[mrep][2][r] + bG);
      float go = sigm(acc[mrep][3][r] + bO);
      size_t ci = (size_t)m * 512 + hj;
      float c2 = gf * Cbuf[ci] + gi * gg;
      Cbuf[ci] = c2;
      Hout[(size_t)m * 640 + 128 + hj] = (h16)(go * tanhf_(c2));
    }
  }
}

// ---------------------------------------------------------------------------
// Head GEMM (encoder x0 + final y[63]) — verified round-2 structure
// ---------------------------------------------------------------------------
__global__ __launch_bounds__(256) void head_gemm2(
    const h16* __restrict__ A, int lda, const h16* __restrict__ Bt,
    const float* __restrict__ bias, int nkt, h16* __restrict__ Xout,
    float* __restrict__ ydst, int tstep) {
  __shared__ __align__(16) h16 As[2][64 * 64];
  __shared__ __align__(16) h16 Bs[2][128 * 64];
  const int tid = threadIdx.x;
  const int lane = tid & 63;
  const int w = tid >> 6;
  const int m0 = blockIdx.x * 64;
  const int arow = lane & 15, khi = lane >> 4;
  const int x7 = arow & 7;

  auto stageA = [&](int slot, int kt) {
#pragma unroll
    for (int li = 0; li < 2; ++li) {
      int rowbase = li * 32 + w * 8;
      int row = rowbase + (lane >> 3);
      int gc = (lane & 7) ^ (lane >> 3);
      gload16(A + (size_t)(m0 + row) * lda + kt * 64 + gc * 8,
              &As[slot][rowbase * 64]);
    }
  };
  auto stageB = [&](int slot, int kt) {
#pragma unroll
    for (int li = 0; li < 4; ++li) {
      int rowbase = li * 32 + w * 8;
      int row = rowbase + (lane >> 3);
      int gc = (lane & 7) ^ (lane >> 3);
      gload16(Bt + (size_t)row * 512 + kt * 64 + gc * 8, &Bs[slot][rowbase * 64]);
    }
  };

  f32x4 acc[8];
#pragma unroll
  for (int jj = 0; jj < 8; ++jj) acc[jj] = (f32x4)0.f;

  stageA(0, 0);
  stageB(0, 0);
#pragma unroll 1
  for (int kt = 0; kt < nkt; ++kt) {
    int p = kt & 1;
    if (kt + 1 < nkt) {
      stageA(p ^ 1, kt + 1);
      stageB(p ^ 1, kt + 1);
      asm volatile("s_waitcnt vmcnt(6)" ::: "memory");
    } else {
      asm volatile("s_waitcnt vmcnt(0)" ::: "memory");
    }
    ENDBAR();
#pragma unroll
    for (int kk = 0; kk < 2; ++kk) {
      int kc = kk * 4 + khi;
      int ra = w * 16 + arow;
      f16x8 afr = *(const f16x8*)&As[p][ra * 64 + (kc ^ x7) * 8];
#pragma unroll
      for (int nt = 0; nt < 8; ++nt) {
        int rb = nt * 16 + arow;
        f16x8 bfr = *(const f16x8*)&Bs[p][rb * 64 + (kc ^ x7) * 8];
        acc[nt] = __builtin_amdgcn_mfma_f32_16x16x32_f16(afr, bfr, acc[nt], 0, 0, 0);
      }
    }
    ENDBAR();
  }

#pragma unroll
  for (int r = 0; r < 4; ++r) {
    int m = m0 + w * 16 + khi * 4 + r;
    float v[8];
    float mx = -1e30f;
#pragma unroll
    for (int nt = 0; nt < 8; ++nt) {
      int col = nt * 16 + arow;
      v[nt] = acc[nt][r] + bias[col];
      if (col != 127) mx = fmaxf(mx, v[nt]);
    }
#pragma unroll
    for (int s = 1; s < 16; s <<= 1) mx = fmaxf(mx, __shfl_xor(mx, s, 16));
    float sm = 0.f;
#pragma unroll
    for (int nt = 0; nt < 8; ++nt) {
      int col = nt * 16 + arow;
      if (col != 127) sm += __expf(v[nt] - mx);
    }
#pragma unroll
    for (int s = 1; s < 16; s <<= 1) sm += __shfl_xor(sm, s, 16);
    float inv = 1.f / sm;
#pragma unroll
    for (int nt = 0; nt < 8; ++nt) {
      int col = nt * 16 + arow;
      float res = (col == 127) ? sigm(v[nt]) : __expf(v[nt] - mx) * inv;
      Xout[(size_t)m * 640 + col] = (h16)res;
      if (ydst) ydst[((size_t)m * 64 + tstep) * 128 + col] = res;
    }
  }
}

// ---------------------------------------------------------------------------
// Encoder GEMM (verified round-1 structure, 128x128 tile)
// ---------------------------------------------------------------------------
enum { EP_LRELU = 0, EP_LIN16 = 1, EP_F32 = 2 };

template <int EP>
__global__ __launch_bounds__(256) void gemm128(
    const h16* __restrict__ A, int lda, const h16* __restrict__ Bt,
    const float* __restrict__ bias, int K, h16* __restrict__ out16, int ldo,
    int ocol, float* __restrict__ outf, int ldf) {
  __shared__ __align__(16) h16 As[128 * 64];
  __shared__ __align__(16) h16 Bs[128 * 64];
  const int tid = threadIdx.x;
  const int lane = tid & 63;
  const int w = tid >> 6;
  const int m0 = blockIdx.x * 128;
  const int n0 = blockIdx.y * 128;

  f32x4 acc[4][4];
#pragma unroll
  for (int i = 0; i < 4; ++i)
#pragma unroll
    for (int jj = 0; jj < 4; ++jj) acc[i][jj] = (f32x4)0.f;

  const int rh = (w >> 1) * 64;
  const int arow = lane & 15;
  const int khi = lane >> 4;

  const int nkt = K >> 6;
  for (int kt = 0; kt < nkt; ++kt) {
#pragma unroll
    for (int li = 0; li < 4; ++li) {
      int L = w * 4 + li;
      int r = L * 8 + (lane >> 3);
      int c = lane & 7;
      int gc = c ^ (r & 7);
      gload16(A + (size_t)(m0 + r) * lda + kt * 64 + gc * 8, &As[L * 512]);
      gload16(Bt + (size_t)(n0 + r) * K + kt * 64 + gc * 8, &Bs[L * 512]);
    }
    __syncthreads();
#pragma unroll
    for (int kk = 0; kk < 2; ++kk) {
      const int kc = kk * 4 + khi;
      f16x8 af[4], bf[4];
#pragma unroll
      for (int mt = 0; mt < 4; ++mt) {
        int r = rh + mt * 16 + arow;
        af[mt] = *(const f16x8*)&As[r * 64 + (kc ^ (r & 7)) * 8];
      }
#pragma unroll
      for (int jj = 0; jj < 4; ++jj) {
        int nt = (w & 1) * 4 + jj;
        int r = nt * 16 + arow;
        bf[jj] = *(const f16x8*)&Bs[r * 64 + (kc ^ (r & 7)) * 8];
      }
#pragma unroll
      for (int mt = 0; mt < 4; ++mt)
#pragma unroll
        for (int jj = 0; jj < 4; ++jj)
          acc[mt][jj] =
              __builtin_amdgcn_mfma_f32_16x16x32_f16(af[mt], bf[jj], acc[mt][jj], 0, 0, 0);
    }
    __syncthreads();
  }

#pragma unroll
  for (int mt = 0; mt < 4; ++mt) {
#pragma unroll
    for (int jj = 0; jj < 4; ++jj) {
      int nt = (w & 1) * 4 + jj;
      int n = n0 + nt * 16 + arow;
      float bv = bias[n];
#pragma unroll
      for (int r = 0; r < 4; ++r) {
        int m = m0 + rh + mt * 16 + khi * 4 + r;
        float v = acc[mt][jj][r] + bv;
        if constexpr (EP == EP_LRELU) {
          v = v >= 0.f ? v : 0.2f * v;
          out16[(size_t)m * ldo + n] = (h16)v;
        } else if constexpr (EP == EP_LIN16) {
          out16[(size_t)m * ldo + ocol + n] = (h16)v;
        } else {
          outf[(size_t)m * ldf + n] = v;
        }
      }
    }
  }
}

// ---------------- prep kernels ----------------
__global__ void cvt16(const float* __restrict__ in, h16* __restrict__ out, int n) {
  int i = blockIdx.x * 256 + threadIdx.x;
  if (i < n) out[i] = (h16)in[i];
}

__global__ void transposeW(const float* __restrict__ W, h16* __restrict__ WT, int K,
                           int N) {
  int i = blockIdx.x * 256 + threadIdx.x;
  if (i >= K * N) return;
  int k = i / N, n = i % N;
  WT[(size_t)n * K + k] = (h16)W[i];
}

// WgT[n'][640]: n' = by*256 + wc*64 + q*16 + jj -> orig = q*512 + by*64 + wc*16 + jj
__global__ void prep_gate(const float* __restrict__ Wih, const float* __restrict__ Whh,
                          const float* __restrict__ bih, const float* __restrict__ bhh,
                          h16* __restrict__ WgT, float* __restrict__ bg) {
  int i = blockIdx.x * 256 + threadIdx.x;
  if (i >= 2048 * 640) return;
  int np = i / 640, k = i % 640;
  int by = np >> 8, wcc = (np >> 6) & 3, q = (np >> 4) & 3, jj = np & 15;
  int orig = q * 512 + by * 64 + wcc * 16 + jj;
  float wv = (k < 128) ? Wih[(size_t)k * 2048 + orig]
                       : Whh[(size_t)(k - 128) * 2048 + orig];
  WgT[i] = (h16)wv;
  if (k == 0) bg[np] = bih[orig] + bhh[orig];
}

// ---------------- launch ----------------
extern "C" void kernel_launch(void* const* d_in, const int* in_sizes, int n_in,
                              void* d_out, int out_size, void* d_ws, size_t ws_size,
                              hipStream_t stream) {
  const float* x = (const float*)d_in[0];
  const float* W1 = (const float*)d_in[1];
  const float* b1 = (const float*)d_in[2];
  const float* W2 = (const float*)d_in[3];
  const float* b2 = (const float*)d_in[4];
  const float* W3 = (const float*)d_in[5];
  const float* b3 = (const float*)d_in[6];
  const float* Wh1 = (const float*)d_in[7];
  const float* bh1 = (const float*)d_in[8];
  const float* Wh2 = (const float*)d_in[9];
  const float* bh2 = (const float*)d_in[10];
  const float* Wc1 = (const float*)d_in[11];
  const float* bc1 = (const float*)d_in[12];
  const float* Wc2 = (const float*)d_in[13];
  const float* bc2 = (const float*)d_in[14];
  const float* Wx1 = (const float*)d_in[15];
  const float* bx1 = (const float*)d_in[16];
  const float* Wx2 = (const float*)d_in[17];
  const float* bx2 = (const float*)d_in[18];
  const float* Wih = (const float*)d_in[19];
  const float* bih = (const float*)d_in[20];
  const float* Whh = (const float*)d_in[21];
  const float* bhh = (const float*)d_in[22];
  const float* Wp = (const float*)d_in[23];
  const float* bp = (const float*)d_in[24];

  char* ws = (char*)d_ws;
  size_t off = 0;
  auto take = [&](size_t bytes) -> void* {
    void* p = ws + off;
    off += (bytes + 255) & ~(size_t)255;
    return p;
  };
  h16* X16 = (h16*)take((size_t)BB * 256 * 2);
  h16* Za = (h16*)take((size_t)BB * 512 * 2);
  h16* Zb = (h16*)take((size_t)BB * 512 * 2);
  h16* XHa = (h16*)take((size_t)BB * 640 * 2);
  h16* XHb = (h16*)take((size_t)BB * 640 * 2);
  float* C = (float*)take((size_t)BB * 512 * 4);
  h16* W1T = (h16*)take(256 * 512 * 2);
  h16* W2T = (h16*)take(512 * 512 * 2);
  h16* W3T = (h16*)take(512 * 512 * 2);
  h16* Wh1T = (h16*)take(512 * 512 * 2);
  h16* Wh2T = (h16*)take(512 * 512 * 2);
  h16* Wc1T = (h16*)take(512 * 512 * 2);
  h16* Wc2T = (h16*)take(512 * 512 * 2);
  h16* Wx1T = (h16*)take(512 * 512 * 2);
  h16* Wx2T = (h16*)take(128 * 512 * 2);
  h16* WpT = (h16*)take(128 * 512 * 2);
  h16* WgT = (h16*)take((size_t)2048 * 640 * 2);
  float* bg = (float*)take(2048 * 4);

  dim3 blk(256);
  cvt16<<<(BB * 256 + 255) / 256, blk, 0, stream>>>(x, X16, BB * 256);
  transposeW<<<(256 * 512 + 255) / 256, blk, 0, stream>>>(W1, W1T, 256, 512);
  transposeW<<<(512 * 512 + 255) / 256, blk, 0, stream>>>(W2, W2T, 512, 512);
  transposeW<<<(512 * 512 + 255) / 256, blk, 0, stream>>>(W3, W3T, 512, 512);
  transposeW<<<(512 * 512 + 255) / 256, blk, 0, stream>>>(Wh1, Wh1T, 512, 512);
  transposeW<<<(512 * 512 + 255) / 256, blk, 0, stream>>>(Wh2, Wh2T, 512, 512);
  transposeW<<<(512 * 512 + 255) / 256, blk, 0, stream>>>(Wc1, Wc1T, 512, 512);
  transposeW<<<(512 * 512 + 255) / 256, blk, 0, stream>>>(Wc2, Wc2T, 512, 512);
  transposeW<<<(512 * 512 + 255) / 256, blk, 0, stream>>>(Wx1, Wx1T, 512, 512);
  transposeW<<<(512 * 128 + 255) / 256, blk, 0, stream>>>(Wx2, Wx2T, 512, 128);
  transposeW<<<(512 * 128 + 255) / 256, blk, 0, stream>>>(Wp, WpT, 512, 128);
  prep_gate<<<(2048 * 640 + 255) / 256, blk, 0, stream>>>(Wih, Whh, bih, bhh, WgT, bg);

  // MLP encoder
  gemm128<EP_LRELU><<<dim3(64, 4), blk, 0, stream>>>(X16, 256, W1T, b1, 256, Za, 512, 0, nullptr, 0);
  gemm128<EP_LRELU><<<dim3(64, 4), blk, 0, stream>>>(Za, 512, W2T, b2, 512, Zb, 512, 0, nullptr, 0);
  gemm128<EP_LRELU><<<dim3(64, 4), blk, 0, stream>>>(Zb, 512, W3T, b3, 512, Za, 512, 0, nullptr, 0);
  gemm128<EP_LRELU><<<dim3(64, 4), blk, 0, stream>>>(Za, 512, Wh1T, bh1, 512, Zb, 512, 0, nullptr, 0);
  gemm128<EP_LIN16><<<dim3(64, 4), blk, 0, stream>>>(Zb, 512, Wh2T, bh2, 512, XHa, 640, 128, nullptr, 0);
  gemm128<EP_LRELU><<<dim3(64, 4), blk, 0, stream>>>(Za, 512, Wc1T, bc1, 512, Zb, 512, 0, nullptr, 0);
  gemm128<EP_F32><<<dim3(64, 4), blk, 0, stream>>>(Zb, 512, Wc2T, bc2, 512, nullptr, 0, 0, C, 512);
  gemm128<EP_LRELU><<<dim3(64, 4), blk, 0, stream>>>(Za, 512, Wx1T, bx1, 512, Zb, 512, 0, nullptr, 0);
  head_gemm2<<<128, blk, 0, stream>>>(Zb, 512, Wx2T, bx2, 8, XHa, nullptr, 0);

  // LSTM decoder: one fused kernel per step (head-in-LDS + gate + cell)
  float* yout = (float*)d_out;
  for (int t = 0; t < TT; ++t) {
    h16* in_ = (t & 1) ? XHb : XHa;
    h16* out_ = (t & 1) ? XHa : XHb;
    gate8<<<dim3(32, 8), dim3(512), 0, stream>>>(in_, WgT, bg, C, out_, WpT, bp,
                                                 yout, t);
  }
  // final y[63] = head(h(64)); h(64) lives in XHa (t=63 odd -> out_=XHa)
  head_gemm2<<<128, blk, 0, stream>>>(XHa + 128, 640, WpT, bp, 8, XHa, yout, 63);
}

// Round 8
// 2839.249 us; speedup vs baseline: 2.0239x; 1.5877x over previous
//
#include <hip/hip_runtime.h>

// ---------------------------------------------------------------------------
// LinearDecoder: MLP encoder -> 64-step LSTM decoder with softmax/sigmoid head
// B=8192, LAT=256, MLP=512, HID=512, INP=128, T=64, gates N=2048, K=640
// R2 macro-structure (verified 2970us): per-step gate8 + head, lockstep.
// head256: full-machine head (256 blocks x 32 rows), XCD-aligned with h writer.
// ---------------------------------------------------------------------------

typedef _Float16 h16;
typedef __attribute__((ext_vector_type(8))) _Float16 f16x8;
typedef __attribute__((ext_vector_type(4))) float f32x4;

#define BB 8192
#define TT 64

__device__ __forceinline__ void gload16(const void* g, void* lds) {
  __builtin_amdgcn_global_load_lds(
      (const __attribute__((address_space(1))) unsigned int*)g,
      (__attribute__((address_space(3))) unsigned int*)lds, 16, 0, 0);
}

__device__ __forceinline__ float sigm(float x) { return 1.f / (1.f + __expf(-x)); }
__device__ __forceinline__ float tanhf_(float x) { return 2.f / (1.f + __expf(-2.f * x)) - 1.f; }

#define MIDBAR_LG()                                        \
  do {                                                     \
    __builtin_amdgcn_s_barrier();                          \
    asm volatile("s_waitcnt lgkmcnt(0)" ::: "memory");     \
    __builtin_amdgcn_sched_barrier(0);                     \
  } while (0)
#define ENDBAR()                                           \
  do {                                                     \
    __builtin_amdgcn_s_barrier();                          \
    asm volatile("" ::: "memory");                         \
  } while (0)

// ---------------------------------------------------------------------------
// 8-phase 256x256 gate GEMM + fused LSTM cell update (verified R2 kernel).
// A = XH [8192][640] fp16; Bt = WgT [2048][640] (permuted); K=640 (10 K-tiles).
// Gate col permutation: n' = by*256 + wc*64 + q*16 + jj
//                       orig = q*512 + (by*64 + wc*16 + jj)
// ---------------------------------------------------------------------------
__global__ __launch_bounds__(512, 2) void gate8(
    const h16* __restrict__ A, const h16* __restrict__ Bt,
    const float* __restrict__ bg, float* __restrict__ Cbuf,
    h16* __restrict__ Hout) {
  __shared__ __align__(16) h16 As[2][16384];
  __shared__ __align__(16) h16 Bs[2][16384];
  const int tid = threadIdx.x;
  const int lane = tid & 63;
  const int wid = tid >> 6;
  const int wr = wid >> 2, wc = wid & 3;
  const int m0 = blockIdx.x * 256;
  const int n0 = blockIdx.y * 256;
  const int arow = lane & 15, khi = lane >> 4;
  const int x7 = arow & 7;

  auto stage = [&](h16(*dst)[16384], int slot, int h, const h16* src, int base,
                   int kt) {
#pragma unroll
    for (int li = 0; li < 2; ++li) {
      int rowbase = li * 128 + h * 64 + wid * 8;  // wave-uniform
      int row = rowbase + (lane >> 3);
      int gc = (lane & 7) ^ (lane >> 3);
      gload16(src + (size_t)(base + row) * 640 + kt * 64 + gc * 8,
              &dst[slot][rowbase * 64]);
    }
  };

  f32x4 acc[8][4];
#pragma unroll
  for (int i = 0; i < 8; ++i)
#pragma unroll
    for (int jj = 0; jj < 4; ++jj) acc[i][jj] = (f32x4)0.f;
  f16x8 af[4], bf[2][4];

  auto readA = [&](int slot, int ms, int ks) {
#pragma unroll
    for (int mr = 0; mr < 4; ++mr) {
      int r = wr * 128 + ms * 64 + mr * 16 + arow;
      af[mr] = *(const f16x8*)&As[slot][r * 64 + ((ks * 4 + khi) ^ x7) * 8];
    }
  };
  auto readB = [&](int slot, int ks) {
#pragma unroll
    for (int jj = 0; jj < 4; ++jj) {
      int rb = wc * 64 + jj * 16 + arow;
      bf[ks][jj] = *(const f16x8*)&Bs[slot][rb * 64 + ((ks * 4 + khi) ^ x7) * 8];
    }
  };
  auto mfma16 = [&](int ms, int ks) {
    __builtin_amdgcn_s_setprio(1);
#pragma unroll
    for (int mr = 0; mr < 4; ++mr)
#pragma unroll
      for (int jj = 0; jj < 4; ++jj)
        acc[ms * 4 + mr][jj] = __builtin_amdgcn_mfma_f32_16x16x32_f16(
            af[mr], bf[ks][jj], acc[ms * 4 + mr][jj], 0, 0, 0);
    __builtin_amdgcn_s_setprio(0);
  };

  // prologue: kt0 fully, kt1 all but A-h1
  stage(Bs, 0, 0, Bt, n0, 0);
  stage(Bs, 0, 1, Bt, n0, 0);
  stage(As, 0, 0, A, m0, 0);
  stage(As, 0, 1, A, m0, 0);
  stage(Bs, 1, 0, Bt, n0, 1);
  stage(Bs, 1, 1, Bt, n0, 1);
  stage(As, 1, 0, A, m0, 1);
  asm volatile("s_waitcnt vmcnt(6)" ::: "memory");
  ENDBAR();

#pragma unroll 1
  for (int i = 0; i < 5; ++i) {
    const int t2 = 2 * i + 2, t3 = 2 * i + 3;
    // P1
    readB(0, 0);
    readB(0, 1);
    readA(0, 0, 0);
    stage(As, 1, 1, A, m0, 2 * i + 1);
    MIDBAR_LG();
    mfma16(0, 0);
    ENDBAR();
    // P2
    readA(0, 0, 1);
    if (t2 < 10) stage(Bs, 0, 0, Bt, n0, t2);
    MIDBAR_LG();
    mfma16(0, 1);
    ENDBAR();
    // P3
    readA(0, 1, 0);
    if (t2 < 10) stage(Bs, 0, 1, Bt, n0, t2);
    MIDBAR_LG();
    mfma16(1, 0);
    ENDBAR();
    // P4
    readA(0, 1, 1);
    if (t2 < 10) stage(As, 0, 0, A, m0, t2);
    if (i < 4)
      asm volatile("s_waitcnt vmcnt(6)" ::: "memory");
    else
      asm volatile("s_waitcnt vmcnt(0)" ::: "memory");
    MIDBAR_LG();
    mfma16(1, 1);
    ENDBAR();
    // P5
    readB(1, 0);
    readB(1, 1);
    readA(1, 0, 0);
    if (t2 < 10) stage(As, 0, 1, A, m0, t2);
    MIDBAR_LG();
    mfma16(0, 0);
    ENDBAR();
    // P6
    readA(1, 0, 1);
    if (t3 < 10) stage(Bs, 1, 0, Bt, n0, t3);
    MIDBAR_LG();
    mfma16(0, 1);
    ENDBAR();
    // P7
    readA(1, 1, 0);
    if (t3 < 10) stage(Bs, 1, 1, Bt, n0, t3);
    MIDBAR_LG();
    mfma16(1, 0);
    ENDBAR();
    // P8
    readA(1, 1, 1);
    if (t3 < 10) stage(As, 1, 0, A, m0, t3);
    if (i < 4)
      asm volatile("s_waitcnt vmcnt(6)" ::: "memory");
    else
      asm volatile("s_waitcnt vmcnt(0)" ::: "memory");
    MIDBAR_LG();
    mfma16(1, 1);
    ENDBAR();
  }

  // ---- gate epilogue: LSTM cell update ----
  const int nb = n0 + wc * 64;
  const float bI = bg[nb + arow];
  const float bF = bg[nb + 16 + arow];
  const float bG = bg[nb + 32 + arow];
  const float bO = bg[nb + 48 + arow];
  const int hj = blockIdx.y * 64 + wc * 16 + arow;
#pragma unroll
  for (int mrep = 0; mrep < 8; ++mrep) {
#pragma unroll
    for (int r = 0; r < 4; ++r) {
      int m = m0 + wr * 128 + mrep * 16 + khi * 4 + r;
      float gi = sigm(acc[mrep][0][r] + bI);
      float gf = sigm(acc[mrep][1][r] + bF);
      float gg = tanhf_(acc[mrep][2][r] + bG);
      float go = sigm(acc[mrep][3][r] + bO);
      size_t ci = (size_t)m * 512 + hj;
      float c2 = gf * Cbuf[ci] + gi * gg;
      Cbuf[ci] = c2;
      Hout[(size_t)m * 640 + 128 + hj] = (h16)(go * tanhf_(c2));
    }
  }
}

// ---------------------------------------------------------------------------
// head256: full-machine head. 256 blocks x 32 rows, 256 thr (4 waves).
// Wave w: row-strip rs = w&1 (16 rows), col-half ch = w>>1 (4 of 8 col-tiles).
// L = A[32,K] @ Bt^T ([128][K]) + bias; softmax(0..126), sigmoid(127).
// swz: align block's XCD (bid%8) with h-writer XCD (mx%8).
// ---------------------------------------------------------------------------
__global__ __launch_bounds__(256) void head256(
    const h16* __restrict__ A, int lda, const h16* __restrict__ Bt,
    const float* __restrict__ bias, int nkt, h16* __restrict__ Xout,
    float* __restrict__ ydst, int tstep, int swz) {
  __shared__ __align__(16) h16 As[2][32 * 64];
  __shared__ __align__(16) h16 Bs[2][128 * 64];
  __shared__ float lgs[32 * 132];  // padded: 132 floats/row kills bank conflict
  const int tid = threadIdx.x;
  const int lane = tid & 63;
  const int w = tid >> 6;
  const int rs = w & 1, ch = w >> 1;
  const int arow = lane & 15, khi = lane >> 4;
  const int x7 = arow & 7;

  int bid = blockIdx.x;
  int m0;
  if (swz) {
    int g = bid & 7, k = bid >> 3;
    m0 = (g + 8 * (k & 3)) * 256 + (k >> 2) * 32;
  } else {
    m0 = bid * 32;
  }

  auto stageA = [&](int slot, int kt) {
    int rowbase = w * 8;  // wave-uniform; 4 waves x 8 rows = 32 rows
    int gc = (lane & 7) ^ (lane >> 3);
    int row = rowbase + (lane >> 3);
    gload16(A + (size_t)(m0 + row) * lda + kt * 64 + gc * 8,
            &As[slot][rowbase * 64]);
  };
  auto stageB = [&](int slot, int kt) {
#pragma unroll
    for (int li = 0; li < 4; ++li) {
      int rowbase = li * 32 + w * 8;
      int row = rowbase + (lane >> 3);
      int gc = (lane & 7) ^ (lane >> 3);
      gload16(Bt + (size_t)row * 512 + kt * 64 + gc * 8, &Bs[slot][rowbase * 64]);
    }
  };

  f32x4 acc[4];
#pragma unroll
  for (int j = 0; j < 4; ++j) acc[j] = (f32x4)0.f;

  stageA(0, 0);
  stageB(0, 0);
#pragma unroll 1
  for (int kt = 0; kt < nkt; ++kt) {
    int p = kt & 1;
    if (kt + 1 < nkt) {
      stageA(p ^ 1, kt + 1);
      stageB(p ^ 1, kt + 1);
      asm volatile("s_waitcnt vmcnt(5)" ::: "memory");
    } else {
      asm volatile("s_waitcnt vmcnt(0)" ::: "memory");
    }
    ENDBAR();
#pragma unroll
    for (int kk = 0; kk < 2; ++kk) {
      int kc = kk * 4 + khi;
      int ra = rs * 16 + arow;
      f16x8 afr = *(const f16x8*)&As[p][ra * 64 + (kc ^ x7) * 8];
#pragma unroll
      for (int j = 0; j < 4; ++j) {
        int rb = (ch * 4 + j) * 16 + arow;
        f16x8 bfr = *(const f16x8*)&Bs[p][rb * 64 + (kc ^ x7) * 8];
        acc[j] = __builtin_amdgcn_mfma_f32_16x16x32_f16(afr, bfr, acc[j], 0, 0, 0);
      }
    }
    ENDBAR();
  }

  // exchange logits through LDS (padded), then per-row softmax/sigmoid
#pragma unroll
  for (int j = 0; j < 4; ++j)
#pragma unroll
    for (int r = 0; r < 4; ++r)
      lgs[(rs * 16 + khi * 4 + r) * 132 + (ch * 4 + j) * 16 + arow] = acc[j][r];
  __syncthreads();
  {
    int row = tid >> 3, g8 = tid & 7;  // 8 threads/row, 16 cols each
    float v[16];
    float mx = -1e30f;
#pragma unroll
    for (int q = 0; q < 16; ++q) {
      int col = g8 * 16 + q;
      v[q] = lgs[row * 132 + col] + bias[col];
      if (col != 127) mx = fmaxf(mx, v[q]);
    }
#pragma unroll
    for (int s = 1; s < 8; s <<= 1) mx = fmaxf(mx, __shfl_xor(mx, s, 8));
    float sm = 0.f;
#pragma unroll
    for (int q = 0; q < 16; ++q) {
      int col = g8 * 16 + q;
      if (col != 127) sm += __expf(v[q] - mx);
    }
#pragma unroll
    for (int s = 1; s < 8; s <<= 1) sm += __shfl_xor(sm, s, 8);
    float inv = 1.f / sm;
    h16 xo[16];
    float yo[16];
#pragma unroll
    for (int q = 0; q < 16; ++q) {
      int col = g8 * 16 + q;
      float res = (col == 127) ? sigm(v[q]) : __expf(v[q] - mx) * inv;
      xo[q] = (h16)res;
      yo[q] = res;
    }
    h16* xd = Xout + (size_t)(m0 + row) * 640 + g8 * 16;
    *(f16x8*)xd = *(f16x8*)&xo[0];
    *(f16x8*)(xd + 8) = *(f16x8*)&xo[8];
    if (ydst) {
      float* yd = ydst + ((size_t)(m0 + row) * 64 + tstep) * 128 + g8 * 16;
#pragma unroll
      for (int q = 0; q < 4; ++q) *(f32x4*)(yd + 4 * q) = *(f32x4*)&yo[4 * q];
    }
  }
}

// ---------------------------------------------------------------------------
// Encoder GEMM (verified round-1 structure, 128x128 tile)
// ---------------------------------------------------------------------------
enum { EP_LRELU = 0, EP_LIN16 = 1, EP_F32 = 2 };

template <int EP>
__global__ __launch_bounds__(256) void gemm128(
    const h16* __restrict__ A, int lda, const h16* __restrict__ Bt,
    const float* __restrict__ bias, int K, h16* __restrict__ out16, int ldo,
    int ocol, float* __restrict__ outf, int ldf) {
  __shared__ __align__(16) h16 As[128 * 64];
  __shared__ __align__(16) h16 Bs[128 * 64];
  const int tid = threadIdx.x;
  const int lane = tid & 63;
  const int w = tid >> 6;
  const int m0 = blockIdx.x * 128;
  const int n0 = blockIdx.y * 128;

  f32x4 acc[4][4];
#pragma unroll
  for (int i = 0; i < 4; ++i)
#pragma unroll
    for (int jj = 0; jj < 4; ++jj) acc[i][jj] = (f32x4)0.f;

  const int rh = (w >> 1) * 64;
  const int arow = lane & 15;
  const int khi = lane >> 4;

  const int nkt = K >> 6;
  for (int kt = 0; kt < nkt; ++kt) {
#pragma unroll
    for (int li = 0; li < 4; ++li) {
      int L = w * 4 + li;
      int r = L * 8 + (lane >> 3);
      int c = lane & 7;
      int gc = c ^ (r & 7);
      gload16(A + (size_t)(m0 + r) * lda + kt * 64 + gc * 8, &As[L * 512]);
      gload16(Bt + (size_t)(n0 + r) * K + kt * 64 + gc * 8, &Bs[L * 512]);
    }
    __syncthreads();
#pragma unroll
    for (int kk = 0; kk < 2; ++kk) {
      const int kc = kk * 4 + khi;
      f16x8 af[4], bf[4];
#pragma unroll
      for (int mt = 0; mt < 4; ++mt) {
        int r = rh + mt * 16 + arow;
        af[mt] = *(const f16x8*)&As[r * 64 + (kc ^ (r & 7)) * 8];
      }
#pragma unroll
      for (int jj = 0; jj < 4; ++jj) {
        int nt = (w & 1) * 4 + jj;
        int r = nt * 16 + arow;
        bf[jj] = *(const f16x8*)&Bs[r * 64 + (kc ^ (r & 7)) * 8];
      }
#pragma unroll
      for (int mt = 0; mt < 4; ++mt)
#pragma unroll
        for (int jj = 0; jj < 4; ++jj)
          acc[mt][jj] =
              __builtin_amdgcn_mfma_f32_16x16x32_f16(af[mt], bf[jj], acc[mt][jj], 0, 0, 0);
    }
    __syncthreads();
  }

#pragma unroll
  for (int mt = 0; mt < 4; ++mt) {
#pragma unroll
    for (int jj = 0; jj < 4; ++jj) {
      int nt = (w & 1) * 4 + jj;
      int n = n0 + nt * 16 + arow;
      float bv = bias[n];
#pragma unroll
      for (int r = 0; r < 4; ++r) {
        int m = m0 + rh + mt * 16 + khi * 4 + r;
        float v = acc[mt][jj][r] + bv;
        if constexpr (EP == EP_LRELU) {
          v = v >= 0.f ? v : 0.2f * v;
          out16[(size_t)m * ldo + n] = (h16)v;
        } else if constexpr (EP == EP_LIN16) {
          out16[(size_t)m * ldo + ocol + n] = (h16)v;
        } else {
          outf[(size_t)m * ldf + n] = v;
        }
      }
    }
  }
}

// ---------------- prep kernels ----------------
__global__ void cvt16(const float* __restrict__ in, h16* __restrict__ out, int n) {
  int i = blockIdx.x * 256 + threadIdx.x;
  if (i < n) out[i] = (h16)in[i];
}

__global__ void transposeW(const float* __restrict__ W, h16* __restrict__ WT, int K,
                           int N) {
  int i = blockIdx.x * 256 + threadIdx.x;
  if (i >= K * N) return;
  int k = i / N, n = i % N;
  WT[(size_t)n * K + k] = (h16)W[i];
}

// WgT[n'][640]: n' = by*256 + wc*64 + q*16 + jj -> orig = q*512 + by*64 + wc*16 + jj
__global__ void prep_gate(const float* __restrict__ Wih, const float* __restrict__ Whh,
                          const float* __restrict__ bih, const float* __restrict__ bhh,
                          h16* __restrict__ WgT, float* __restrict__ bg) {
  int i = blockIdx.x * 256 + threadIdx.x;
  if (i >= 2048 * 640) return;
  int np = i / 640, k = i % 640;
  int by = np >> 8, wcc = (np >> 6) & 3, q = (np >> 4) & 3, jj = np & 15;
  int orig = q * 512 + by * 64 + wcc * 16 + jj;
  float wv = (k < 128) ? Wih[(size_t)k * 2048 + orig]
                       : Whh[(size_t)(k - 128) * 2048 + orig];
  WgT[i] = (h16)wv;
  if (k == 0) bg[np] = bih[orig] + bhh[orig];
}

// ---------------- launch ----------------
extern "C" void kernel_launch(void* const* d_in, const int* in_sizes, int n_in,
                              void* d_out, int out_size, void* d_ws, size_t ws_size,
                              hipStream_t stream) {
  const float* x = (const float*)d_in[0];
  const float* W1 = (const float*)d_in[1];
  const float* b1 = (const float*)d_in[2];
  const float* W2 = (const float*)d_in[3];
  const float* b2 = (const float*)d_in[4];
  const float* W3 = (const float*)d_in[5];
  const float* b3 = (const float*)d_in[6];
  const float* Wh1 = (const float*)d_in[7];
  const float* bh1 = (const float*)d_in[8];
  const float* Wh2 = (const float*)d_in[9];
  const float* bh2 = (const float*)d_in[10];
  const float* Wc1 = (const float*)d_in[11];
  const float* bc1 = (const float*)d_in[12];
  const float* Wc2 = (const float*)d_in[13];
  const float* bc2 = (const float*)d_in[14];
  const float* Wx1 = (const float*)d_in[15];
  const float* bx1 = (const float*)d_in[16];
  const float* Wx2 = (const float*)d_in[17];
  const float* bx2 = (const float*)d_in[18];
  const float* Wih = (const float*)d_in[19];
  const float* bih = (const float*)d_in[20];
  const float* Whh = (const float*)d_in[21];
  const float* bhh = (const float*)d_in[22];
  const float* Wp = (const float*)d_in[23];
  const float* bp = (const float*)d_in[24];

  char* ws = (char*)d_ws;
  size_t off = 0;
  auto take = [&](size_t bytes) -> void* {
    void* p = ws + off;
    off += (bytes + 255) & ~(size_t)255;
    return p;
  };
  h16* X16 = (h16*)take((size_t)BB * 256 * 2);
  h16* Za = (h16*)take((size_t)BB * 512 * 2);
  h16* Zb = (h16*)take((size_t)BB * 512 * 2);
  h16* XHa = (h16*)take((size_t)BB * 640 * 2);
  h16* XHb = (h16*)take((size_t)BB * 640 * 2);
  float* C = (float*)take((size_t)BB * 512 * 4);
  h16* W1T = (h16*)take(256 * 512 * 2);
  h16* W2T = (h16*)take(512 * 512 * 2);
  h16* W3T = (h16*)take(512 * 512 * 2);
  h16* Wh1T = (h16*)take(512 * 512 * 2);
  h16* Wh2T = (h16*)take(512 * 512 * 2);
  h16* Wc1T = (h16*)take(512 * 512 * 2);
  h16* Wc2T = (h16*)take(512 * 512 * 2);
  h16* Wx1T = (h16*)take(512 * 512 * 2);
  h16* Wx2T = (h16*)take(128 * 512 * 2);
  h16* WpT = (h16*)take(128 * 512 * 2);
  h16* WgT = (h16*)take((size_t)2048 * 640 * 2);
  float* bg = (float*)take(2048 * 4);

  dim3 blk(256);
  cvt16<<<(BB * 256 + 255) / 256, blk, 0, stream>>>(x, X16, BB * 256);
  transposeW<<<(256 * 512 + 255) / 256, blk, 0, stream>>>(W1, W1T, 256, 512);
  transposeW<<<(512 * 512 + 255) / 256, blk, 0, stream>>>(W2, W2T, 512, 512);
  transposeW<<<(512 * 512 + 255) / 256, blk, 0, stream>>>(W3, W3T, 512, 512);
  transposeW<<<(512 * 512 + 255) / 256, blk, 0, stream>>>(Wh1, Wh1T, 512, 512);
  transposeW<<<(512 * 512 + 255) / 256, blk, 0, stream>>>(Wh2, Wh2T, 512, 512);
  transposeW<<<(512 * 512 + 255) / 256, blk, 0, stream>>>(Wc1, Wc1T, 512, 512);
  transposeW<<<(512 * 512 + 255) / 256, blk, 0, stream>>>(Wc2, Wc2T, 512, 512);
  transposeW<<<(512 * 512 + 255) / 256, blk, 0, stream>>>(Wx1, Wx1T, 512, 512);
  transposeW<<<(512 * 128 + 255) / 256, blk, 0, stream>>>(Wx2, Wx2T, 512, 128);
  transposeW<<<(512 * 128 + 255) / 256, blk, 0, stream>>>(Wp, WpT, 512, 128);
  prep_gate<<<(2048 * 640 + 255) / 256, blk, 0, stream>>>(Wih, Whh, bih, bhh, WgT, bg);

  // MLP encoder
  gemm128<EP_LRELU><<<dim3(64, 4), blk, 0, stream>>>(X16, 256, W1T, b1, 256, Za, 512, 0, nullptr, 0);
  gemm128<EP_LRELU><<<dim3(64, 4), blk, 0, stream>>>(Za, 512, W2T, b2, 512, Zb, 512, 0, nullptr, 0);
  gemm128<EP_LRELU><<<dim3(64, 4), blk, 0, stream>>>(Zb, 512, W3T, b3, 512, Za, 512, 0, nullptr, 0);
  gemm128<EP_LRELU><<<dim3(64, 4), blk, 0, stream>>>(Za, 512, Wh1T, bh1, 512, Zb, 512, 0, nullptr, 0);
  gemm128<EP_LIN16><<<dim3(64, 4), blk, 0, stream>>>(Zb, 512, Wh2T, bh2, 512, XHa, 640, 128, nullptr, 0);
  gemm128<EP_LRELU><<<dim3(64, 4), blk, 0, stream>>>(Za, 512, Wc1T, bc1, 512, Zb, 512, 0, nullptr, 0);
  gemm128<EP_F32><<<dim3(64, 4), blk, 0, stream>>>(Zb, 512, Wc2T, bc2, 512, nullptr, 0, 0, C, 512);
  gemm128<EP_LRELU><<<dim3(64, 4), blk, 0, stream>>>(Za, 512, Wx1T, bx1, 512, Zb, 512, 0, nullptr, 0);
  head256<<<256, blk, 0, stream>>>(Zb, 512, Wx2T, bx2, 8, XHa, nullptr, 0, 0);

  // LSTM decoder: per-step gate + full-machine head (lockstep, verified macro)
  float* yout = (float*)d_out;
  for (int t = 0; t < TT; ++t) {
    h16* in_ = (t & 1) ? XHb : XHa;
    h16* out_ = (t & 1) ? XHa : XHb;
    gate8<<<dim3(32, 8), dim3(512), 0, stream>>>(in_, WgT, bg, C, out_);
    head256<<<256, blk, 0, stream>>>(out_ + 128, 640, WpT, bp, 8, out_, yout, t, 1);
  }
}